// Round 4
// baseline (524.134 us; speedup 1.0000x reference)
//
#include <hip/hip_runtime.h>

#define D 512
typedef unsigned short ushort_t;
typedef __attribute__((ext_vector_type(8))) short bf16x8;
typedef __attribute__((ext_vector_type(4))) float f32x4;

static __device__ __forceinline__ ushort_t f2bf(float f) {
  unsigned u = __float_as_uint(f);
  u += 0x7fffu + ((u >> 16) & 1u);  // RNE
  return (ushort_t)(u >> 16);
}
static __device__ __forceinline__ float bf2f(ushort_t h) {
  return __uint_as_float(((unsigned)h) << 16);
}

static __device__ __forceinline__ void gld_lds16(const void* g, void* lds) {
  __builtin_amdgcn_global_load_lds(
      (const __attribute__((address_space(1))) unsigned int*)g,
      (__attribute__((address_space(3))) unsigned int*)lds, 16, 0, 0);
}

// ---------- weight pack: W[K][N] fp32 -> fragment-ready bf16 ----------
__global__ __launch_bounds__(256) void pack_weight(
    const float* __restrict__ W, ushort_t* __restrict__ out, int K, int N) {
  int i = blockIdx.x * 256 + threadIdx.x;
  if (i >= K * N) return;
  const int k = i / N, n = i - k * N;
  const int nt = n >> 4, col = n & 15, kt = k >> 5, kg = (k >> 3) & 3, j = k & 7;
  out[(((size_t)nt * (K >> 5) + kt) << 9) + ((kg << 4) + col) * 8 + j] = f2bf(W[i]);
}

// ---------- fp32 -> bf16 row-major with row padding ----------
__global__ __launch_bounds__(256) void conv_bf16_pad(
    const float* __restrict__ in, ushort_t* __restrict__ out, int M, int Mp, int K) {
  const size_t i4 = ((size_t)blockIdx.x * 256 + threadIdx.x) * 4;
  if (i4 >= (size_t)Mp * K) return;
  const int row = (int)(i4 / K);
  ushort4 o;
  if (row < M) {
    const float4 v = *reinterpret_cast<const float4*>(&in[i4]);
    o.x = f2bf(v.x); o.y = f2bf(v.y); o.z = f2bf(v.z); o.w = f2bf(v.w);
  } else {
    o.x = o.y = o.z = o.w = 0;
  }
  *reinterpret_cast<ushort4*>(&out[i4]) = o;
}

// ---------- MFMA GEMM with optional row-indirection and fused att-dots ----
// C[M,N] = A[rowidx?][K](bf16) @ Wpack + bias ; optional sd/ss atomic dots
__global__ __launch_bounds__(256) void gemm_mfma(
    const ushort_t* __restrict__ A, const ushort_t* __restrict__ Bp,
    const float* __restrict__ bias, float* __restrict__ C32,
    ushort_t* __restrict__ C16, const int* __restrict__ rowidx,
    const float* __restrict__ watt, float* __restrict__ sdp,
    float* __restrict__ ssp, int Mlim, int N, int K) {
  __shared__ __align__(16) ushort_t As[8 * 512];
  __shared__ __align__(16) ushort_t Bs[8 * 512];
  const int tid = threadIdx.x;
  const int lane = tid & 63;
  const int wid = tid >> 6;
  const int m0 = blockIdx.y * 128;
  const int n0 = blockIdx.x * 128;
  const int wm = wid >> 1, wn = wid & 1;
  const int arow = lane & 15;
  const int akoff = (lane >> 4) * 8;
  const int kt32 = K >> 5;
  const int r0g = m0 + (wid * 2 + 0) * 16 + arow;
  const int r1g = m0 + (wid * 2 + 1) * 16 + arow;
  const int ar0 = rowidx ? rowidx[r0g] : r0g;
  const int ar1 = rowidx ? rowidx[r1g] : r1g;
  f32x4 acc[4][4] = {};
  ushort_t* as0 = &As[(wid * 2 + 0) * 512];
  ushort_t* as1 = &As[(wid * 2 + 1) * 512];
  ushort_t* bs0 = &Bs[(wid * 2 + 0) * 512];
  ushort_t* bs1 = &Bs[(wid * 2 + 1) * 512];
  for (int k0 = 0; k0 < K; k0 += 32) {
    gld_lds16(&A[(size_t)ar0 * K + k0 + akoff], as0);
    gld_lds16(&A[(size_t)ar1 * K + k0 + akoff], as1);
    const ushort_t* gb0 = &Bp[(((size_t)(n0 / 16 + wid * 2 + 0) * kt32 + (k0 >> 5)) << 9) + lane * 8];
    const ushort_t* gb1 = &Bp[(((size_t)(n0 / 16 + wid * 2 + 1) * kt32 + (k0 >> 5)) << 9) + lane * 8];
    gld_lds16(gb0, bs0);
    gld_lds16(gb1, bs1);
    __syncthreads();
    bf16x8 af[4], bf[4];
#pragma unroll
    for (int mi = 0; mi < 4; ++mi)
      af[mi] = *reinterpret_cast<const bf16x8*>(&As[(wm * 4 + mi) * 512 + lane * 8]);
#pragma unroll
    for (int ni = 0; ni < 4; ++ni)
      bf[ni] = *reinterpret_cast<const bf16x8*>(&Bs[(wn * 4 + ni) * 512 + lane * 8]);
#pragma unroll
    for (int mi = 0; mi < 4; ++mi)
#pragma unroll
      for (int ni = 0; ni < 4; ++ni)
        acc[mi][ni] = __builtin_amdgcn_mfma_f32_16x16x32_bf16(af[mi], bf[ni], acc[mi][ni], 0, 0, 0);
    __syncthreads();
  }
  // epilogue: C/D layout col=lane&15, row=(lane>>4)*4+r
#pragma unroll
  for (int mi = 0; mi < 4; ++mi) {
    const int rowb = m0 + wm * 64 + mi * 16 + ((lane >> 4) << 2);
#pragma unroll
    for (int r = 0; r < 4; ++r) {
      float psd = 0.f, pss = 0.f;
#pragma unroll
      for (int ni = 0; ni < 4; ++ni) {
        const int col = n0 + wn * 64 + ni * 16 + (lane & 15);
        const float v = acc[mi][ni][r] + bias[col];
        const size_t o = (size_t)(rowb + r) * N + col;
        if (C32) C32[o] = v;
        if (C16) C16[o] = f2bf(v);
        if (watt) { psd += v * watt[col]; pss += v * watt[D + col]; }
      }
      if (watt) {
#pragma unroll
        for (int off = 8; off > 0; off >>= 1) {
          psd += __shfl_xor(psd, off);
          pss += __shfl_xor(pss, off);
        }
        if ((lane & 15) == 0 && rowb + r < Mlim) {
          atomicAdd(&sdp[rowb + r], psd);
          atomicAdd(&ssp[rowb + r], pss);
        }
      }
    }
  }
}

// ---------- CSR build (both hops, concatenated segment space) ----------
__global__ void count_deg2(const int* __restrict__ e1, const int* __restrict__ e0,
                           int* __restrict__ deg, int Nn, int E) {
  const int e = blockIdx.x * blockDim.x + threadIdx.x;
  if (e < E) {
    atomicAdd(&deg[e1[e]], 1);
    atomicAdd(&deg[Nn + e0[e]], 1);
  }
}

__global__ __launch_bounds__(256) void scan_block(
    const int* __restrict__ deg, int* __restrict__ incl, int* __restrict__ bsum, int n) {
  __shared__ int buf[256];
  const int t = threadIdx.x;
  const int i = blockIdx.x * 256 + t;
  const int v = (i < n) ? deg[i] : 0;
  buf[t] = v;
  __syncthreads();
  for (int off = 1; off < 256; off <<= 1) {
    const int y = (t >= off) ? buf[t - off] : 0;
    __syncthreads();
    buf[t] += y;
    __syncthreads();
  }
  if (i < n) incl[i] = buf[t];
  if (t == 255) bsum[blockIdx.x] = buf[255];
}

__global__ __launch_bounds__(256) void scan_sums(
    int* __restrict__ bsum, int nb, int* __restrict__ row_total) {
  __shared__ int buf[256];
  const int t = threadIdx.x;
  const int v = (t < nb) ? bsum[t] : 0;
  buf[t] = v;
  __syncthreads();
  for (int off = 1; off < 256; off <<= 1) {
    const int y = (t >= off) ? buf[t - off] : 0;
    __syncthreads();
    buf[t] += y;
    __syncthreads();
  }
  if (t < nb) bsum[t] = buf[t] - v;  // exclusive
  if (t == 0) *row_total = buf[255];
}

__global__ __launch_bounds__(256) void scan_finalize(
    const int* __restrict__ incl, const int* __restrict__ deg,
    const int* __restrict__ bsum, int* __restrict__ row_start,
    int* __restrict__ cursor, int n) {
  const int i = blockIdx.x * 256 + threadIdx.x;
  if (i >= n) return;
  const int v = incl[i] - deg[i] + bsum[i >> 8];
  row_start[i] = v;
  cursor[i] = v;
}

__global__ void fill_csr2(const int* __restrict__ e1, const int* __restrict__ e0,
                          int* __restrict__ cursor, int* __restrict__ csr_s,
                          int Nn, int E) {
  const int e = blockIdx.x * blockDim.x + threadIdx.x;
  if (e >= E) return;
  const int d1 = e1[e];
  csr_s[atomicAdd(&cursor[d1], 1)] = e1[E + e];
  const int d0 = e0[e];
  csr_s[atomicAdd(&cursor[Nn + d0], 1)] = e0[E + e];
}

// ---------- GAT softmax + aggregate, one wave per dst ----------
__global__ __launch_bounds__(256) void gat_aggregate_w(
    ushort_t* __restrict__ featb, const ushort_t* __restrict__ hb,
    const float* __restrict__ sd, const float* __restrict__ ss,
    float* __restrict__ edge_e, const float* __restrict__ b_att_p,
    const float* __restrict__ gat_bias, const int* __restrict__ row_start,
    const int* __restrict__ csr_src, int Nn) {
  const int dst = blockIdx.x * 4 + (threadIdx.x >> 6);
  const int lane = threadIdx.x & 63;
  if (dst >= Nn) return;
  const int beg = row_start[dst];
  const int end = row_start[dst + 1];
  const int deg = end - beg;
  const float sdd = sd[dst];
  const float ba = b_att_p[0];
  float acc[8] = {};
  float inv;
  if (deg <= 64) {
    // fully in-register path
    const int j0 = beg + lane;
    const bool valid = j0 < end;
    const float e = valid ? tanhf(sdd + ss[csr_src[j0]] + ba) : -1e30f;
    float m = e;
#pragma unroll
    for (int off = 32; off > 0; off >>= 1) m = fmaxf(m, __shfl_xor(m, off));
    float a = valid ? expf(e - m) : 0.f;
    float s = a;
#pragma unroll
    for (int off = 32; off > 0; off >>= 1) s += __shfl_xor(s, off);
    inv = (s > 0.f) ? 1.f / s : 0.f;
    int k = 0;
    for (; k + 1 < deg; k += 2) {
      const float w0 = __shfl(a, k) * inv;
      const float w1 = __shfl(a, k + 1) * inv;
      const int s0 = csr_src[beg + k];
      const int s1 = csr_src[beg + k + 1];
      const bf16x8 h0 = *reinterpret_cast<const bf16x8*>(&hb[(size_t)s0 * D + lane * 8]);
      const bf16x8 h1 = *reinterpret_cast<const bf16x8*>(&hb[(size_t)s1 * D + lane * 8]);
#pragma unroll
      for (int q = 0; q < 8; ++q)
        acc[q] += w0 * bf2f((ushort_t)h0[q]) + w1 * bf2f((ushort_t)h1[q]);
    }
    if (k < deg) {
      const float w = __shfl(a, k) * inv;
      const int s0 = csr_src[beg + k];
      const bf16x8 h0 = *reinterpret_cast<const bf16x8*>(&hb[(size_t)s0 * D + lane * 8]);
#pragma unroll
      for (int q = 0; q < 8; ++q) acc[q] += w * bf2f((ushort_t)h0[q]);
    }
  } else {
    // spill path via edge_e (rare)
    float m = -1e30f;
    for (int j = beg + lane; j < end; j += 64) {
      const float e = tanhf(sdd + ss[csr_src[j]] + ba);
      edge_e[j] = e;
      m = fmaxf(m, e);
    }
#pragma unroll
    for (int off = 32; off > 0; off >>= 1) m = fmaxf(m, __shfl_xor(m, off));
    asm volatile("s_waitcnt vmcnt(0)" ::: "memory");
    float s = 0.f;
    for (int j = beg + lane; j < end; j += 64) {
      const float a2 = expf(edge_e[j] - m);
      edge_e[j] = a2;
      s += a2;
    }
#pragma unroll
    for (int off = 32; off > 0; off >>= 1) s += __shfl_xor(s, off);
    asm volatile("s_waitcnt vmcnt(0)" ::: "memory");
    inv = (s > 0.f) ? 1.f / s : 0.f;
    for (int j = beg; j < end; ++j) {
      const float w = edge_e[j] * inv;
      const int sidx = csr_src[j];
      const bf16x8 hv = *reinterpret_cast<const bf16x8*>(&hb[(size_t)sidx * D + lane * 8]);
#pragma unroll
      for (int q = 0; q < 8; ++q) acc[q] += w * bf2f((ushort_t)hv[q]);
    }
  }
  const size_t o = (size_t)dst * D + lane * 8;
  bf16x8 fv = *reinterpret_cast<const bf16x8*>(&featb[o]);
#pragma unroll
  for (int q = 0; q < 8; ++q) {
    const float f = (bf2f((ushort_t)fv[q]) + acc[q] + gat_bias[lane * 8 + q]) * 0.5f;
    fv[q] = (short)f2bf(f);
  }
  *reinterpret_cast<bf16x8*>(&featb[o]) = fv;
}

// ---------- fused tanh + LayerNorm, wave per row ----------
__global__ __launch_bounds__(256) void tanh_ln_w(
    const float* __restrict__ xa, const float* __restrict__ xb,
    const float* __restrict__ g, const float* __restrict__ beta,
    float* __restrict__ out32, ushort_t* __restrict__ out16, int Mrows) {
  const int r = blockIdx.x * 4 + (threadIdx.x >> 6);
  const int lane = threadIdx.x & 63;
  if (r >= Mrows) return;
  const size_t base = (size_t)r * D + lane * 8;
  float v[8];
  {
    const float4 a0 = *reinterpret_cast<const float4*>(&xa[base]);
    const float4 a1 = *reinterpret_cast<const float4*>(&xa[base + 4]);
    v[0] = a0.x; v[1] = a0.y; v[2] = a0.z; v[3] = a0.w;
    v[4] = a1.x; v[5] = a1.y; v[6] = a1.z; v[7] = a1.w;
  }
  if (xb) {
    const float4 b0 = *reinterpret_cast<const float4*>(&xb[base]);
    const float4 b1 = *reinterpret_cast<const float4*>(&xb[base + 4]);
    v[0] += b0.x; v[1] += b0.y; v[2] += b0.z; v[3] += b0.w;
    v[4] += b1.x; v[5] += b1.y; v[6] += b1.z; v[7] += b1.w;
  }
  float sum = 0.f, sq = 0.f;
#pragma unroll
  for (int q = 0; q < 8; ++q) {
    v[q] = tanhf(v[q]);
    sum += v[q];
    sq += v[q] * v[q];
  }
#pragma unroll
  for (int off = 32; off > 0; off >>= 1) {
    sum += __shfl_xor(sum, off);
    sq += __shfl_xor(sq, off);
  }
  const float mean = sum * (1.f / (float)D);
  const float var = sq * (1.f / (float)D) - mean * mean;
  const float rs = rsqrtf(var + 1e-5f);
  float o[8];
#pragma unroll
  for (int q = 0; q < 8; ++q)
    o[q] = (v[q] - mean) * rs * g[lane * 8 + q] + beta[lane * 8 + q];
  if (out32) {
    *reinterpret_cast<float4*>(&out32[base]) = make_float4(o[0], o[1], o[2], o[3]);
    *reinterpret_cast<float4*>(&out32[base + 4]) = make_float4(o[4], o[5], o[6], o[7]);
  }
  if (out16) {
    bf16x8 ob;
#pragma unroll
    for (int q = 0; q < 8; ++q) ob[q] = (short)f2bf(o[q]);
    *reinterpret_cast<bf16x8*>(&out16[base]) = ob;
  }
}

// ---------- final logits + sigmoid, wave per row ----------
__global__ __launch_bounds__(256) void final_logit_w(
    const float* __restrict__ h, const float* __restrict__ Wc,
    const float* __restrict__ bc, float* __restrict__ out, int Mrows) {
  const int r = blockIdx.x * 4 + (threadIdx.x >> 6);
  const int lane = threadIdx.x & 63;
  if (r >= Mrows) return;
  const size_t base = (size_t)r * D + lane * 8;
  float p = 0.f;
#pragma unroll
  for (int q = 0; q < 8; ++q) p += h[base + q] * Wc[lane * 8 + q];
#pragma unroll
  for (int off = 32; off > 0; off >>= 1) p += __shfl_xor(p, off);
  if (lane == 0) out[r] = 1.f / (1.f + expf(-(p + bc[0])));
}

extern "C" void kernel_launch(void* const* d_in, const int* in_sizes, int n_in,
                              void* d_out, int out_size, void* d_ws, size_t ws_size,
                              hipStream_t stream) {
  (void)n_in; (void)out_size; (void)ws_size;
  const float* node_feat = (const float*)d_in[0];
  const int* edge0 = (const int*)d_in[1];
  const int* edge1 = (const int*)d_in[2];
  const int* tidx = (const int*)d_in[3];
  const float* Wt = (const float*)d_in[4];
  const float* bt = (const float*)d_in[5];
  const float* Wf = (const float*)d_in[6];
  const float* bfp = (const float*)d_in[7];
  const float* w_att = (const float*)d_in[8];
  const float* b_att = (const float*)d_in[9];
  const float* gat_bias = (const float*)d_in[10];
  const float* Wp = (const float*)d_in[11];
  const float* bp = (const float*)d_in[12];
  const float* dnn_W = (const float*)d_in[13];
  const float* dnn_b = (const float*)d_in[14];
  const float* dnn_g = (const float*)d_in[15];
  const float* dnn_be = (const float*)d_in[16];
  const float* res_g = (const float*)d_in[17];
  const float* res_be = (const float*)d_in[18];
  const float* Wc = (const float*)d_in[19];
  const float* bc = (const float*)d_in[20];
  float* out = (float*)d_out;

  const int Nn = in_sizes[0] / D;   // 30000
  const int E = in_sizes[1] / 2;    // 300000
  const int B = in_sizes[3];        // 4096
  const int K_IN = in_sizes[4] / D; // 512
  const int Mp = (Nn + 127) / 128 * 128;
  const int N2 = 2 * Nn;

  char* p = (char*)d_ws;
  auto alloc = [&](size_t bytes) -> char* {
    char* r = p;
    p += (bytes + 255) & ~(size_t)255;
    return r;
  };
  ushort_t* featb = (ushort_t*)alloc((size_t)Mp * D * 2);
  ushort_t* hb = (ushort_t*)alloc((size_t)Mp * D * 2);  // also nfb before hop GEMMs
  float* sdss = (float*)alloc((size_t)N2 * 4);          // sd | ss contiguous
  float* sd = sdss;
  float* ss = sdss + Nn;
  int* deg = (int*)alloc((size_t)N2 * 4);
  int* incl = (int*)alloc((size_t)N2 * 4);
  int* bsum = (int*)alloc(256 * 4);
  int* cursor = (int*)alloc((size_t)N2 * 4);
  int* row_start = (int*)alloc((size_t)(N2 + 1) * 4);
  int* csr_s = (int*)alloc((size_t)2 * E * 4);
  float* edge_e = (float*)alloc((size_t)2 * E * 4);
  ushort_t* pWt = (ushort_t*)alloc((size_t)K_IN * D * 2);
  ushort_t* pWf = (ushort_t*)alloc((size_t)D * D * 2);
  ushort_t* pWp = (ushort_t*)alloc((size_t)D * D * 2);
  ushort_t* pDW[4];
  for (int i = 0; i < 4; ++i) pDW[i] = (ushort_t*)alloc((size_t)D * D * 2);
  float* cur32 = (float*)alloc((size_t)B * D * 4);
  ushort_t* curb = (ushort_t*)alloc((size_t)B * D * 2);
  float* tmp32 = (float*)alloc((size_t)B * D * 4);
  float* ln32 = (float*)alloc((size_t)B * D * 4);
  ushort_t* lnb = (ushort_t*)alloc((size_t)B * D * 2);

  dim3 blk(256);
  const int nb2 = (N2 + 255) / 256;
  const int nw4 = (Nn + 3) / 4;

  // ---- one-time packs / converts ----
  {
    const int wg = (D * D + 255) / 256;
    pack_weight<<<(K_IN * D + 255) / 256, blk, 0, stream>>>(Wt, pWt, K_IN, D);
    pack_weight<<<wg, blk, 0, stream>>>(Wf, pWf, D, D);
    pack_weight<<<wg, blk, 0, stream>>>(Wp, pWp, D, D);
    for (int i = 0; i < 4; ++i)
      pack_weight<<<wg, blk, 0, stream>>>(dnn_W + (size_t)i * D * D, pDW[i], D, D);
    conv_bf16_pad<<<((size_t)Mp * K_IN / 4 + 255) / 256, blk, 0, stream>>>(
        node_feat, hb /*nfb*/, Nn, Mp, K_IN);
  }

  // ---- CSR for both hops in one pass (hop1 -> segment 0, hop0 -> segment 1)
  hipMemsetAsync(deg, 0, (size_t)N2 * 4, stream);
  count_deg2<<<(E + 255) / 256, blk, 0, stream>>>(edge1, edge0, deg, Nn, E);
  scan_block<<<nb2, blk, 0, stream>>>(deg, incl, bsum, N2);
  scan_sums<<<1, blk, 0, stream>>>(bsum, nb2, &row_start[N2]);
  scan_finalize<<<nb2, blk, 0, stream>>>(incl, deg, bsum, row_start, cursor, N2);
  fill_csr2<<<(E + 255) / 256, blk, 0, stream>>>(edge1, edge0, cursor, csr_s, Nn, E);

  // ---- feat = node_feat @ Wt + bt (bf16 out) ----
  {
    dim3 grid(D / 128, Mp / 128);
    gemm_mfma<<<grid, blk, 0, stream>>>(hb /*nfb*/, pWt, bt, nullptr, featb,
                                        nullptr, nullptr, nullptr, nullptr, 0, D, K_IN);
  }

  // ---- two GAT hops (h-GEMM with fused attention dots) ----
  for (int hp = 0; hp < 2; ++hp) {
    dim3 grid(D / 128, Mp / 128);
    hipMemsetAsync(sdss, 0, (size_t)N2 * 4, stream);
    gemm_mfma<<<grid, blk, 0, stream>>>(featb, pWf, bfp, nullptr, hb,
                                        nullptr, w_att, sd, ss, Nn, D, D);
    gat_aggregate_w<<<nw4, blk, 0, stream>>>(featb, hb, sd, ss, edge_e, b_att,
                                             gat_bias, row_start + hp * Nn, csr_s, Nn);
  }

  // ---- head ----
  dim3 gridh(D / 128, B / 128);
  // first head GEMM reads featb rows via target_idx indirection
  gemm_mfma<<<gridh, blk, 0, stream>>>(featb, pWp, bp, cur32, curb,
                                       tidx, nullptr, nullptr, nullptr, 0, D, D);
  const int hb4 = B / 4;
  for (int r = 0; r < 2; ++r) {
    gemm_mfma<<<gridh, blk, 0, stream>>>(curb, pDW[r * 2], dnn_b + (size_t)(r * 2) * D,
                                         tmp32, nullptr, nullptr, nullptr, nullptr, nullptr, 0, D, D);
    tanh_ln_w<<<hb4, blk, 0, stream>>>(tmp32, nullptr, dnn_g + (size_t)(r * 2) * D,
                                       dnn_be + (size_t)(r * 2) * D, nullptr, lnb, B);
    gemm_mfma<<<gridh, blk, 0, stream>>>(lnb, pDW[r * 2 + 1], dnn_b + (size_t)(r * 2 + 1) * D,
                                         tmp32, nullptr, nullptr, nullptr, nullptr, nullptr, 0, D, D);
    tanh_ln_w<<<hb4, blk, 0, stream>>>(tmp32, nullptr, dnn_g + (size_t)(r * 2 + 1) * D,
                                       dnn_be + (size_t)(r * 2 + 1) * D, ln32, nullptr, B);
    tanh_ln_w<<<hb4, blk, 0, stream>>>(cur32, ln32, res_g + (size_t)r * D,
                                       res_be + (size_t)r * D, tmp32, curb, B);
    float* t = cur32; cur32 = tmp32; tmp32 = t;
  }
  final_logit_w<<<hb4, blk, 0, stream>>>(cur32, Wc, bc, out, B);
}

// Round 5
// 409.041 us; speedup vs baseline: 1.2814x; 1.2814x over previous
//
#include <hip/hip_runtime.h>

#define D 512
typedef unsigned short ushort_t;
typedef __attribute__((ext_vector_type(8))) short bf16x8;
typedef __attribute__((ext_vector_type(4))) float f32x4;

static __device__ __forceinline__ ushort_t f2bf(float f) {
  unsigned u = __float_as_uint(f);
  u += 0x7fffu + ((u >> 16) & 1u);  // RNE
  return (ushort_t)(u >> 16);
}
static __device__ __forceinline__ float bf2f(ushort_t h) {
  return __uint_as_float(((unsigned)h) << 16);
}

static __device__ __forceinline__ void gld_lds16(const void* g, void* lds) {
  __builtin_amdgcn_global_load_lds(
      (const __attribute__((address_space(1))) unsigned int*)g,
      (__attribute__((address_space(3))) unsigned int*)lds, 16, 0, 0);
}

// ---------- weight pack: W[K][N] fp32 -> fragment-ready bf16 ----------
// dst[((nt*(K/32)+kt)<<9) + (kg*16+col)*8 + j] = W[kt*32+kg*8+j][nt*16+col]
__global__ __launch_bounds__(256) void pack_weight(
    const float* __restrict__ W, ushort_t* __restrict__ out, int K, int N) {
  int i = blockIdx.x * 256 + threadIdx.x;
  if (i >= K * N) return;
  const int k = i / N, n = i - k * N;
  const int nt = n >> 4, col = n & 15, kt = k >> 5, kg = (k >> 3) & 3, j = k & 7;
  out[(((size_t)nt * (K >> 5) + kt) << 9) + ((kg << 4) + col) * 8 + j] = f2bf(W[i]);
}

// ---------- fp32 -> bf16 row-major with row padding ----------
__global__ __launch_bounds__(256) void conv_bf16_pad(
    const float* __restrict__ in, ushort_t* __restrict__ out, int M, int Mp, int K) {
  const size_t i4 = ((size_t)blockIdx.x * 256 + threadIdx.x) * 4;
  if (i4 >= (size_t)Mp * K) return;
  const int row = (int)(i4 / K);
  ushort4 o;
  if (row < M) {
    const float4 v = *reinterpret_cast<const float4*>(&in[i4]);
    o.x = f2bf(v.x); o.y = f2bf(v.y); o.z = f2bf(v.z); o.w = f2bf(v.w);
  } else {
    o.x = o.y = o.z = o.w = 0;
  }
  *reinterpret_cast<ushort4*>(&out[i4]) = o;
}

// ---------- node MFMA GEMM: C16[M,N] = A[M,K](bf16) @ Wpack + bias ----------
// 128x128 tile, 4 waves, BK=32, XCD-bijective-swizzled 1D grid (NBX=4 cols).
__global__ __launch_bounds__(256) void gemm_mfma(
    const ushort_t* __restrict__ A, const ushort_t* __restrict__ Bp,
    const float* __restrict__ bias, ushort_t* __restrict__ C16, int N, int K) {
  __shared__ __align__(16) ushort_t As[8 * 512];
  __shared__ __align__(16) ushort_t Bs[8 * 512];
  // bijective XCD swizzle (m204): contiguous wgid chunks per XCD
  const int nwg = gridDim.x;
  const int q = nwg >> 3, rm = nwg & 7;
  const int xcd = blockIdx.x & 7, kk = blockIdx.x >> 3;
  const int lin = (xcd < rm ? xcd * (q + 1) : rm * (q + 1) + (xcd - rm) * q) + kk;
  const int m0 = (lin >> 2) * 128;
  const int n0 = (lin & 3) * 128;
  const int tid = threadIdx.x;
  const int lane = tid & 63;
  const int wid = tid >> 6;
  const int wm = wid >> 1, wn = wid & 1;
  const int arow = lane & 15;
  const int akoff = (lane >> 4) * 8;
  const int kt32 = K >> 5;
  f32x4 acc[4][4] = {};
  ushort_t* as0 = &As[(wid * 2 + 0) * 512];
  ushort_t* as1 = &As[(wid * 2 + 1) * 512];
  ushort_t* bs0 = &Bs[(wid * 2 + 0) * 512];
  ushort_t* bs1 = &Bs[(wid * 2 + 1) * 512];
  for (int k0 = 0; k0 < K; k0 += 32) {
    gld_lds16(&A[(size_t)(m0 + (wid * 2 + 0) * 16 + arow) * K + k0 + akoff], as0);
    gld_lds16(&A[(size_t)(m0 + (wid * 2 + 1) * 16 + arow) * K + k0 + akoff], as1);
    gld_lds16(&Bp[(((size_t)(n0 / 16 + wid * 2 + 0) * kt32 + (k0 >> 5)) << 9) + lane * 8], bs0);
    gld_lds16(&Bp[(((size_t)(n0 / 16 + wid * 2 + 1) * kt32 + (k0 >> 5)) << 9) + lane * 8], bs1);
    __syncthreads();
    bf16x8 af[4], bfr[4];
#pragma unroll
    for (int mi = 0; mi < 4; ++mi)
      af[mi] = *reinterpret_cast<const bf16x8*>(&As[(wm * 4 + mi) * 512 + lane * 8]);
#pragma unroll
    for (int ni = 0; ni < 4; ++ni)
      bfr[ni] = *reinterpret_cast<const bf16x8*>(&Bs[(wn * 4 + ni) * 512 + lane * 8]);
#pragma unroll
    for (int mi = 0; mi < 4; ++mi)
#pragma unroll
      for (int ni = 0; ni < 4; ++ni)
        acc[mi][ni] = __builtin_amdgcn_mfma_f32_16x16x32_bf16(af[mi], bfr[ni], acc[mi][ni], 0, 0, 0);
    __syncthreads();
  }
#pragma unroll
  for (int mi = 0; mi < 4; ++mi) {
    const int row = m0 + wm * 64 + mi * 16 + ((lane >> 4) << 2);
#pragma unroll
    for (int ni = 0; ni < 4; ++ni) {
      const int col = n0 + wn * 64 + ni * 16 + (lane & 15);
      const float bv = bias[col];
#pragma unroll
      for (int r = 0; r < 4; ++r)
        C16[(size_t)(row + r) * N + col] = f2bf(acc[mi][ni][r] + bv);
    }
  }
}

// ---------- per-row double dot, one wave per row ----------
__global__ __launch_bounds__(256) void rowdot2_w(
    const ushort_t* __restrict__ hb, const float* __restrict__ w_att,
    float* __restrict__ sd, float* __restrict__ ss, int Nn) {
  const int r = blockIdx.x * 4 + (threadIdx.x >> 6);
  const int lane = threadIdx.x & 63;
  if (r >= Nn) return;
  const bf16x8 hv = *reinterpret_cast<const bf16x8*>(&hb[(size_t)r * D + lane * 8]);
  float d0 = 0.f, d1 = 0.f;
#pragma unroll
  for (int q = 0; q < 8; ++q) {
    const float v = bf2f((ushort_t)hv[q]);
    d0 += v * w_att[lane * 8 + q];
    d1 += v * w_att[D + lane * 8 + q];
  }
#pragma unroll
  for (int off = 32; off > 0; off >>= 1) {
    d0 += __shfl_xor(d0, off);
    d1 += __shfl_xor(d1, off);
  }
  if (lane == 0) { sd[r] = d0; ss[r] = d1; }
}

// ---------- CSR build (both hops, concatenated segment space) ----------
__global__ void count_deg2(const int* __restrict__ e1, const int* __restrict__ e0,
                           int* __restrict__ deg, int Nn, int E) {
  const int e = blockIdx.x * blockDim.x + threadIdx.x;
  if (e < E) {
    atomicAdd(&deg[e1[e]], 1);
    atomicAdd(&deg[Nn + e0[e]], 1);
  }
}

__global__ __launch_bounds__(256) void scan_block(
    const int* __restrict__ deg, int* __restrict__ incl, int* __restrict__ bsum, int n) {
  __shared__ int buf[256];
  const int t = threadIdx.x;
  const int i = blockIdx.x * 256 + t;
  const int v = (i < n) ? deg[i] : 0;
  buf[t] = v;
  __syncthreads();
  for (int off = 1; off < 256; off <<= 1) {
    const int y = (t >= off) ? buf[t - off] : 0;
    __syncthreads();
    buf[t] += y;
    __syncthreads();
  }
  if (i < n) incl[i] = buf[t];
  if (t == 255) bsum[blockIdx.x] = buf[255];
}

__global__ __launch_bounds__(256) void scan_sums(
    int* __restrict__ bsum, int nb, int* __restrict__ row_total) {
  __shared__ int buf[256];
  const int t = threadIdx.x;
  const int v = (t < nb) ? bsum[t] : 0;
  buf[t] = v;
  __syncthreads();
  for (int off = 1; off < 256; off <<= 1) {
    const int y = (t >= off) ? buf[t - off] : 0;
    __syncthreads();
    buf[t] += y;
    __syncthreads();
  }
  if (t < nb) bsum[t] = buf[t] - v;  // exclusive
  if (t == 0) *row_total = buf[255];
}

__global__ __launch_bounds__(256) void scan_finalize(
    const int* __restrict__ incl, const int* __restrict__ deg,
    const int* __restrict__ bsum, int* __restrict__ row_start,
    int* __restrict__ cursor, int n) {
  const int i = blockIdx.x * 256 + threadIdx.x;
  if (i >= n) return;
  const int v = incl[i] - deg[i] + bsum[i >> 8];
  row_start[i] = v;
  cursor[i] = v;
}

__global__ void fill_csr2(const int* __restrict__ e1, const int* __restrict__ e0,
                          int* __restrict__ cursor, int* __restrict__ csr_s,
                          int Nn, int E) {
  const int e = blockIdx.x * blockDim.x + threadIdx.x;
  if (e >= E) return;
  const int d1 = e1[e];
  csr_s[atomicAdd(&cursor[d1], 1)] = e1[E + e];
  const int d0 = e0[e];
  csr_s[atomicAdd(&cursor[Nn + d0], 1)] = e0[E + e];
}

// ---------- GAT softmax + aggregate, one wave per dst ----------
__global__ __launch_bounds__(256) void gat_aggregate_w(
    ushort_t* __restrict__ featb, const ushort_t* __restrict__ hb,
    const float* __restrict__ sd, const float* __restrict__ ss,
    float* __restrict__ edge_e, const float* __restrict__ b_att_p,
    const float* __restrict__ gat_bias, const int* __restrict__ row_start,
    const int* __restrict__ csr_src, int Nn) {
  const int dst = blockIdx.x * 4 + (threadIdx.x >> 6);
  const int lane = threadIdx.x & 63;
  if (dst >= Nn) return;
  const int beg = row_start[dst];
  const int end = row_start[dst + 1];
  const int deg = end - beg;
  const float sdd = sd[dst];
  const float ba = b_att_p[0];
  float acc[8] = {};
  float inv;
  if (deg <= 64) {
    const int j0 = beg + lane;
    const bool valid = j0 < end;
    const float e = valid ? tanhf(sdd + ss[csr_src[j0]] + ba) : -1e30f;
    float m = e;
#pragma unroll
    for (int off = 32; off > 0; off >>= 1) m = fmaxf(m, __shfl_xor(m, off));
    float a = valid ? expf(e - m) : 0.f;
    float s = a;
#pragma unroll
    for (int off = 32; off > 0; off >>= 1) s += __shfl_xor(s, off);
    inv = (s > 0.f) ? 1.f / s : 0.f;
    int k = 0;
    for (; k + 1 < deg; k += 2) {
      const float w0 = __shfl(a, k) * inv;
      const float w1 = __shfl(a, k + 1) * inv;
      const int s0 = csr_src[beg + k];
      const int s1 = csr_src[beg + k + 1];
      const bf16x8 h0 = *reinterpret_cast<const bf16x8*>(&hb[(size_t)s0 * D + lane * 8]);
      const bf16x8 h1 = *reinterpret_cast<const bf16x8*>(&hb[(size_t)s1 * D + lane * 8]);
#pragma unroll
      for (int q = 0; q < 8; ++q)
        acc[q] += w0 * bf2f((ushort_t)h0[q]) + w1 * bf2f((ushort_t)h1[q]);
    }
    if (k < deg) {
      const float w = __shfl(a, k) * inv;
      const int s0 = csr_src[beg + k];
      const bf16x8 h0 = *reinterpret_cast<const bf16x8*>(&hb[(size_t)s0 * D + lane * 8]);
#pragma unroll
      for (int q = 0; q < 8; ++q) acc[q] += w * bf2f((ushort_t)h0[q]);
    }
  } else {
    float m = -1e30f;
    for (int j = beg + lane; j < end; j += 64) {
      const float e = tanhf(sdd + ss[csr_src[j]] + ba);
      edge_e[j] = e;
      m = fmaxf(m, e);
    }
#pragma unroll
    for (int off = 32; off > 0; off >>= 1) m = fmaxf(m, __shfl_xor(m, off));
    asm volatile("s_waitcnt vmcnt(0)" ::: "memory");
    float s = 0.f;
    for (int j = beg + lane; j < end; j += 64) {
      const float a2 = expf(edge_e[j] - m);
      edge_e[j] = a2;
      s += a2;
    }
#pragma unroll
    for (int off = 32; off > 0; off >>= 1) s += __shfl_xor(s, off);
    asm volatile("s_waitcnt vmcnt(0)" ::: "memory");
    inv = (s > 0.f) ? 1.f / s : 0.f;
    for (int j = beg; j < end; ++j) {
      const float w = edge_e[j] * inv;
      const int sidx = csr_src[j];
      const bf16x8 hv = *reinterpret_cast<const bf16x8*>(&hb[(size_t)sidx * D + lane * 8]);
#pragma unroll
      for (int q = 0; q < 8; ++q) acc[q] += w * bf2f((ushort_t)hv[q]);
    }
  }
  const size_t o = (size_t)dst * D + lane * 8;
  bf16x8 fv = *reinterpret_cast<const bf16x8*>(&featb[o]);
#pragma unroll
  for (int q = 0; q < 8; ++q) {
    const float f = (bf2f((ushort_t)fv[q]) + acc[q] + gat_bias[lane * 8 + q]) * 0.5f;
    fv[q] = (short)f2bf(f);
  }
  *reinterpret_cast<bf16x8*>(&featb[o]) = fv;
}

// ---------- fused head: gather -> Wp -> 2x(2x(GEMM,tanh,LN), res LN) -> logit
// 512 threads (8 waves), one block per 16 batch rows. Weights from L2.
__global__ __launch_bounds__(512) void head_fused(
    const ushort_t* __restrict__ featb, const int* __restrict__ tidx,
    const ushort_t* __restrict__ pWp, const float* __restrict__ bp,
    const ushort_t* __restrict__ pDW, const float* __restrict__ dnn_b,
    const float* __restrict__ dnn_g, const float* __restrict__ dnn_be,
    const float* __restrict__ res_g, const float* __restrict__ res_be,
    const float* __restrict__ Wc, const float* __restrict__ bc,
    float* __restrict__ out) {
  __shared__ __align__(16) ushort_t A_lds[16 * 512];
  __shared__ float lsum[8][16], lsq[8][16], meanv[16], rsv[16];
  const int tid = threadIdx.x;
  const int lane = tid & 63;
  const int wave = tid >> 6;
  const int nt0 = wave * 4;       // 4 n-tiles (64 cols) per wave
  const int c15 = lane & 15;      // A-frag row / output col-in-tile
  const int rgrp = lane >> 4;     // output row group

  // gather 16 target rows into swizzled A_lds
  for (int c = tid; c < 1024; c += 512) {
    const int row = c >> 6, col8 = c & 63;
    const int g = tidx[blockIdx.x * 16 + row];
    const bf16x8 v = *reinterpret_cast<const bf16x8*>(&featb[(size_t)g * D + col8 * 8]);
    *reinterpret_cast<bf16x8*>(&A_lds[row * 512 + (col8 ^ (row & 7)) * 8]) = v;
  }
  __syncthreads();

  auto do_gemm = [&](const ushort_t* __restrict__ W, f32x4* acc) {
#pragma unroll
    for (int ni = 0; ni < 4; ++ni) acc[ni] = f32x4{0.f, 0.f, 0.f, 0.f};
    for (int kt = 0; kt < 16; ++kt) {
      const int col8 = kt * 4 + rgrp;
      const bf16x8 af = *reinterpret_cast<const bf16x8*>(
          &A_lds[c15 * 512 + (col8 ^ (c15 & 7)) * 8]);
#pragma unroll
      for (int ni = 0; ni < 4; ++ni) {
        const bf16x8 bfr = *reinterpret_cast<const bf16x8*>(
            &W[(((size_t)(nt0 + ni) * 16 + kt) << 9) + lane * 8]);
        acc[ni] = __builtin_amdgcn_mfma_f32_16x16x32_bf16(af, bfr, acc[ni], 0, 0, 0);
      }
    }
  };

  auto block_ln = [&](f32x4* v, const float* __restrict__ g,
                      const float* __restrict__ be) {
    float psum[4], psq[4];
#pragma unroll
    for (int r = 0; r < 4; ++r) { psum[r] = 0.f; psq[r] = 0.f; }
#pragma unroll
    for (int ni = 0; ni < 4; ++ni)
#pragma unroll
      for (int r = 0; r < 4; ++r) {
        psum[r] += v[ni][r];
        psq[r] += v[ni][r] * v[ni][r];
      }
#pragma unroll
    for (int off = 8; off > 0; off >>= 1)
#pragma unroll
      for (int r = 0; r < 4; ++r) {
        psum[r] += __shfl_xor(psum[r], off);
        psq[r] += __shfl_xor(psq[r], off);
      }
    if (c15 == 0) {
#pragma unroll
      for (int r = 0; r < 4; ++r) {
        lsum[wave][rgrp * 4 + r] = psum[r];
        lsq[wave][rgrp * 4 + r] = psq[r];
      }
    }
    __syncthreads();
    if (tid < 16) {
      float s = 0.f, qq = 0.f;
#pragma unroll
      for (int w = 0; w < 8; ++w) { s += lsum[w][tid]; qq += lsq[w][tid]; }
      const float mean = s * (1.f / 512.f);
      const float var = qq * (1.f / 512.f) - mean * mean;
      meanv[tid] = mean;
      rsv[tid] = rsqrtf(var + 1e-5f);
    }
    __syncthreads();
#pragma unroll
    for (int ni = 0; ni < 4; ++ni) {
      const int col = (nt0 + ni) * 16 + c15;
      const float gg = g[col], bb = be[col];
#pragma unroll
      for (int r = 0; r < 4; ++r) {
        const int row = rgrp * 4 + r;
        v[ni][r] = (v[ni][r] - meanv[row]) * rsv[row] * gg + bb;
      }
    }
  };

  auto store_A = [&](const f32x4* v) {
#pragma unroll
    for (int ni = 0; ni < 4; ++ni) {
      const int col = (nt0 + ni) * 16 + c15;
#pragma unroll
      for (int r = 0; r < 4; ++r) {
        const int row = rgrp * 4 + r;
        A_lds[row * 512 + (((col >> 3) ^ (row & 7)) << 3) + (col & 7)] =
            f2bf(v[ni][r]);
      }
    }
  };

  f32x4 sc[4], acc[4], ln[4];

  // stage 0: sc = A @ Wp + bp
  do_gemm(pWp, acc);
#pragma unroll
  for (int ni = 0; ni < 4; ++ni) {
    const float bv = bp[(nt0 + ni) * 16 + c15];
#pragma unroll
    for (int r = 0; r < 4; ++r) sc[ni][r] = acc[ni][r] + bv;
  }
  __syncthreads();
  store_A(sc);
  __syncthreads();

  for (int rb = 0; rb < 2; ++rb) {
    // dnn stage 2rb
    {
      const int st = rb * 2;
      do_gemm(pDW + (size_t)st * D * D, acc);
#pragma unroll
      for (int ni = 0; ni < 4; ++ni) {
        const float bv = dnn_b[st * D + (nt0 + ni) * 16 + c15];
#pragma unroll
        for (int r = 0; r < 4; ++r) acc[ni][r] = tanhf(acc[ni][r] + bv);
      }
      block_ln(acc, dnn_g + st * D, dnn_be + st * D);
      store_A(acc);   // safe: block_ln's barriers fence prior A_lds reads
      __syncthreads();
    }
    // dnn stage 2rb+1
    {
      const int st = rb * 2 + 1;
      do_gemm(pDW + (size_t)st * D * D, ln);
#pragma unroll
      for (int ni = 0; ni < 4; ++ni) {
        const float bv = dnn_b[st * D + (nt0 + ni) * 16 + c15];
#pragma unroll
        for (int r = 0; r < 4; ++r) ln[ni][r] = tanhf(ln[ni][r] + bv);
      }
      block_ln(ln, dnn_g + st * D, dnn_be + st * D);
    }
    // residual: sc = LN(tanh(sc + ln))
#pragma unroll
    for (int ni = 0; ni < 4; ++ni)
#pragma unroll
      for (int r = 0; r < 4; ++r) acc[ni][r] = tanhf(sc[ni][r] + ln[ni][r]);
    block_ln(acc, res_g + rb * D, res_be + rb * D);
#pragma unroll
    for (int ni = 0; ni < 4; ++ni) sc[ni] = acc[ni];
    if (rb == 0) {
      store_A(sc);
      __syncthreads();
    }
  }

  // final logit + sigmoid
  float pr[4];
#pragma unroll
  for (int r = 0; r < 4; ++r) pr[r] = 0.f;
#pragma unroll
  for (int ni = 0; ni < 4; ++ni) {
    const float wv = Wc[(nt0 + ni) * 16 + c15];
#pragma unroll
    for (int r = 0; r < 4; ++r) pr[r] += sc[ni][r] * wv;
  }
#pragma unroll
  for (int off = 8; off > 0; off >>= 1)
#pragma unroll
    for (int r = 0; r < 4; ++r) pr[r] += __shfl_xor(pr[r], off);
  __syncthreads();  // fence lsum reuse
  if (c15 == 0) {
#pragma unroll
    for (int r = 0; r < 4; ++r) lsum[wave][rgrp * 4 + r] = pr[r];
  }
  __syncthreads();
  if (tid < 16) {
    float s = 0.f;
#pragma unroll
    for (int w = 0; w < 8; ++w) s += lsum[w][tid];
    out[blockIdx.x * 16 + tid] = 1.f / (1.f + expf(-(s + bc[0])));
  }
}

extern "C" void kernel_launch(void* const* d_in, const int* in_sizes, int n_in,
                              void* d_out, int out_size, void* d_ws, size_t ws_size,
                              hipStream_t stream) {
  (void)n_in; (void)out_size; (void)ws_size;
  const float* node_feat = (const float*)d_in[0];
  const int* edge0 = (const int*)d_in[1];
  const int* edge1 = (const int*)d_in[2];
  const int* tidx = (const int*)d_in[3];
  const float* Wt = (const float*)d_in[4];
  const float* bt = (const float*)d_in[5];
  const float* Wf = (const float*)d_in[6];
  const float* bfp = (const float*)d_in[7];
  const float* w_att = (const float*)d_in[8];
  const float* b_att = (const float*)d_in[9];
  const float* gat_bias = (const float*)d_in[10];
  const float* Wp = (const float*)d_in[11];
  const float* bp = (const float*)d_in[12];
  const float* dnn_W = (const float*)d_in[13];
  const float* dnn_b = (const float*)d_in[14];
  const float* dnn_g = (const float*)d_in[15];
  const float* dnn_be = (const float*)d_in[16];
  const float* res_g = (const float*)d_in[17];
  const float* res_be = (const float*)d_in[18];
  const float* Wc = (const float*)d_in[19];
  const float* bc = (const float*)d_in[20];
  float* out = (float*)d_out;

  const int Nn = in_sizes[0] / D;   // 30000
  const int E = in_sizes[1] / 2;    // 300000
  const int B = in_sizes[3];        // 4096
  const int K_IN = in_sizes[4] / D; // 512
  const int Mp = (Nn + 127) / 128 * 128;
  const int N2 = 2 * Nn;

  char* p = (char*)d_ws;
  auto alloc = [&](size_t bytes) -> char* {
    char* r = p;
    p += (bytes + 255) & ~(size_t)255;
    return r;
  };
  ushort_t* featb = (ushort_t*)alloc((size_t)Mp * D * 2);
  ushort_t* hb = (ushort_t*)alloc((size_t)Mp * D * 2);  // also nfb pre-hop
  float* sd = (float*)alloc((size_t)Nn * 4);
  float* ss = (float*)alloc((size_t)Nn * 4);
  int* deg = (int*)alloc((size_t)N2 * 4);
  int* incl = (int*)alloc((size_t)N2 * 4);
  int* bsum = (int*)alloc(256 * 4);
  int* cursor = (int*)alloc((size_t)N2 * 4);
  int* row_start = (int*)alloc((size_t)(N2 + 1) * 4);
  int* csr_s = (int*)alloc((size_t)2 * E * 4);
  float* edge_e = (float*)alloc((size_t)2 * E * 4);
  ushort_t* pWt = (ushort_t*)alloc((size_t)K_IN * D * 2);
  ushort_t* pWf = (ushort_t*)alloc((size_t)D * D * 2);
  ushort_t* pWp = (ushort_t*)alloc((size_t)D * D * 2);
  ushort_t* pDWall = (ushort_t*)alloc((size_t)4 * D * D * 2);

  dim3 blk(256);
  const int nb2 = (N2 + 255) / 256;
  const int nw4 = (Nn + 3) / 4;

  // ---- one-time packs / converts ----
  {
    const int wg = (D * D + 255) / 256;
    pack_weight<<<(K_IN * D + 255) / 256, blk, 0, stream>>>(Wt, pWt, K_IN, D);
    pack_weight<<<wg, blk, 0, stream>>>(Wf, pWf, D, D);
    pack_weight<<<wg, blk, 0, stream>>>(Wp, pWp, D, D);
    for (int i = 0; i < 4; ++i)
      pack_weight<<<wg, blk, 0, stream>>>(dnn_W + (size_t)i * D * D,
                                          pDWall + (size_t)i * D * D, D, D);
    conv_bf16_pad<<<((size_t)Mp * K_IN / 4 + 255) / 256, blk, 0, stream>>>(
        node_feat, hb /*nfb*/, Nn, Mp, K_IN);
  }

  // ---- CSR for both hops (hop1 -> segment 0, hop0 -> segment 1) ----
  hipMemsetAsync(deg, 0, (size_t)N2 * 4, stream);
  count_deg2<<<(E + 255) / 256, blk, 0, stream>>>(edge1, edge0, deg, Nn, E);
  scan_block<<<nb2, blk, 0, stream>>>(deg, incl, bsum, N2);
  scan_sums<<<1, blk, 0, stream>>>(bsum, nb2, &row_start[N2]);
  scan_finalize<<<nb2, blk, 0, stream>>>(incl, deg, bsum, row_start, cursor, N2);
  fill_csr2<<<(E + 255) / 256, blk, 0, stream>>>(edge1, edge0, cursor, csr_s, Nn, E);

  // ---- feat = node_feat @ Wt + bt ----
  gemm_mfma<<<dim3(4 * (Mp / 128)), blk, 0, stream>>>(hb, pWt, bt, featb, D, K_IN);

  // ---- two GAT hops ----
  for (int hp = 0; hp < 2; ++hp) {
    gemm_mfma<<<dim3(4 * (Mp / 128)), blk, 0, stream>>>(featb, pWf, bfp, hb, D, D);
    rowdot2_w<<<nw4, blk, 0, stream>>>(hb, w_att, sd, ss, Nn);
    gat_aggregate_w<<<nw4, blk, 0, stream>>>(featb, hb, sd, ss, edge_e, b_att,
                                             gat_bias, row_start + hp * Nn, csr_s, Nn);
  }

  // ---- fused head ----
  head_fused<<<B / 16, dim3(512), 0, stream>>>(
      featb, tidx, pWp, bp, pDWall, dnn_b, dnn_g, dnn_be, res_g, res_be,
      Wc, bc, out);
}

// Round 6
// 357.788 us; speedup vs baseline: 1.4649x; 1.1433x over previous
//
#include <hip/hip_runtime.h>

#define D 512
typedef unsigned short ushort_t;
typedef __attribute__((ext_vector_type(8))) short bf16x8;
typedef __attribute__((ext_vector_type(4))) float f32x4;

static __device__ __forceinline__ ushort_t f2bf(float f) {
  unsigned u = __float_as_uint(f);
  u += 0x7fffu + ((u >> 16) & 1u);  // RNE
  return (ushort_t)(u >> 16);
}
static __device__ __forceinline__ float bf2f(ushort_t h) {
  return __uint_as_float(((unsigned)h) << 16);
}

static __device__ __forceinline__ void gld_lds16(const void* g, void* lds) {
  __builtin_amdgcn_global_load_lds(
      (const __attribute__((address_space(1))) unsigned int*)g,
      (__attribute__((address_space(3))) unsigned int*)lds, 16, 0, 0);
}

// ---------- weight pack: nmat x W[K][N] fp32 -> fragment-ready bf16 ----------
// dst[((nt*(K/32)+kt)<<9) + (kg*16+col)*8 + j] = W[kt*32+kg*8+j][nt*16+col]
__global__ __launch_bounds__(256) void pack_weight(
    const float* __restrict__ W, ushort_t* __restrict__ out, int K, int N, int nmat) {
  int i = blockIdx.x * 256 + threadIdx.x;
  const int per = K * N;
  if (i >= per * nmat) return;
  const int mat = i / per;
  const int r = i - mat * per;
  const int k = r / N, n = r - k * N;
  const int nt = n >> 4, col = n & 15, kt = k >> 5, kg = (k >> 3) & 3, j = k & 7;
  out[(size_t)mat * per + (((size_t)nt * (K >> 5) + kt) << 9) + ((kg << 4) + col) * 8 + j] =
      f2bf(W[(size_t)mat * per + r]);
}

// ---------- fp32 -> bf16 row-major with row padding ----------
__global__ __launch_bounds__(256) void conv_bf16_pad(
    const float* __restrict__ in, ushort_t* __restrict__ out, int M, int Mp, int K) {
  const size_t i4 = ((size_t)blockIdx.x * 256 + threadIdx.x) * 4;
  if (i4 >= (size_t)Mp * K) return;
  const int row = (int)(i4 / K);
  ushort4 o;
  if (row < M) {
    const float4 v = *reinterpret_cast<const float4*>(&in[i4]);
    o.x = f2bf(v.x); o.y = f2bf(v.y); o.z = f2bf(v.z); o.w = f2bf(v.w);
  } else {
    o.x = o.y = o.z = o.w = 0;
  }
  *reinterpret_cast<ushort4*>(&out[i4]) = o;
}

// ---------- node MFMA GEMM: C16[M,N] = A[M,K](bf16) @ Wpack + bias ----------
// 128x128 tile, 4 waves, BK=32, XCD-bijective-swizzled 1D grid (NBX=4 cols).
__global__ __launch_bounds__(256) void gemm_mfma(
    const ushort_t* __restrict__ A, const ushort_t* __restrict__ Bp,
    const float* __restrict__ bias, ushort_t* __restrict__ C16, int N, int K) {
  __shared__ __align__(16) ushort_t As[8 * 512];
  __shared__ __align__(16) ushort_t Bs[8 * 512];
  const int nwg = gridDim.x;
  const int q = nwg >> 3, rm = nwg & 7;
  const int xcd = blockIdx.x & 7, kk = blockIdx.x >> 3;
  const int lin = (xcd < rm ? xcd * (q + 1) : rm * (q + 1) + (xcd - rm) * q) + kk;
  const int m0 = (lin >> 2) * 128;
  const int n0 = (lin & 3) * 128;
  const int tid = threadIdx.x;
  const int lane = tid & 63;
  const int wid = tid >> 6;
  const int wm = wid >> 1, wn = wid & 1;
  const int arow = lane & 15;
  const int akoff = (lane >> 4) * 8;
  const int kt32 = K >> 5;
  f32x4 acc[4][4] = {};
  ushort_t* as0 = &As[(wid * 2 + 0) * 512];
  ushort_t* as1 = &As[(wid * 2 + 1) * 512];
  ushort_t* bs0 = &Bs[(wid * 2 + 0) * 512];
  ushort_t* bs1 = &Bs[(wid * 2 + 1) * 512];
  for (int k0 = 0; k0 < K; k0 += 32) {
    gld_lds16(&A[(size_t)(m0 + (wid * 2 + 0) * 16 + arow) * K + k0 + akoff], as0);
    gld_lds16(&A[(size_t)(m0 + (wid * 2 + 1) * 16 + arow) * K + k0 + akoff], as1);
    gld_lds16(&Bp[(((size_t)(n0 / 16 + wid * 2 + 0) * kt32 + (k0 >> 5)) << 9) + lane * 8], bs0);
    gld_lds16(&Bp[(((size_t)(n0 / 16 + wid * 2 + 1) * kt32 + (k0 >> 5)) << 9) + lane * 8], bs1);
    __syncthreads();
    bf16x8 af[4], bfr[4];
#pragma unroll
    for (int mi = 0; mi < 4; ++mi)
      af[mi] = *reinterpret_cast<const bf16x8*>(&As[(wm * 4 + mi) * 512 + lane * 8]);
#pragma unroll
    for (int ni = 0; ni < 4; ++ni)
      bfr[ni] = *reinterpret_cast<const bf16x8*>(&Bs[(wn * 4 + ni) * 512 + lane * 8]);
#pragma unroll
    for (int mi = 0; mi < 4; ++mi)
#pragma unroll
      for (int ni = 0; ni < 4; ++ni)
        acc[mi][ni] = __builtin_amdgcn_mfma_f32_16x16x32_bf16(af[mi], bfr[ni], acc[mi][ni], 0, 0, 0);
    __syncthreads();
  }
#pragma unroll
  for (int mi = 0; mi < 4; ++mi) {
    const int row = m0 + wm * 64 + mi * 16 + ((lane >> 4) << 2);
#pragma unroll
    for (int ni = 0; ni < 4; ++ni) {
      const int col = n0 + wn * 64 + ni * 16 + (lane & 15);
      const float bv = bias[col];
#pragma unroll
      for (int r = 0; r < 4; ++r)
        C16[(size_t)(row + r) * N + col] = f2bf(acc[mi][ni][r] + bv);
    }
  }
}

// ---------- per-row double dot, one wave per row ----------
__global__ __launch_bounds__(256) void rowdot2_w(
    const ushort_t* __restrict__ hb, const float* __restrict__ w_att,
    float* __restrict__ sd, float* __restrict__ ss, int Nn) {
  const int r = blockIdx.x * 4 + (threadIdx.x >> 6);
  const int lane = threadIdx.x & 63;
  if (r >= Nn) return;
  const bf16x8 hv = *reinterpret_cast<const bf16x8*>(&hb[(size_t)r * D + lane * 8]);
  float d0 = 0.f, d1 = 0.f;
#pragma unroll
  for (int q = 0; q < 8; ++q) {
    const float v = bf2f((ushort_t)hv[q]);
    d0 += v * w_att[lane * 8 + q];
    d1 += v * w_att[D + lane * 8 + q];
  }
#pragma unroll
  for (int off = 32; off > 0; off >>= 1) {
    d0 += __shfl_xor(d0, off);
    d1 += __shfl_xor(d1, off);
  }
  if (lane == 0) { sd[r] = d0; ss[r] = d1; }
}

// ---------- CSR build (both hops, concatenated segment space) ----------
__global__ void count_deg2(const int* __restrict__ e1, const int* __restrict__ e0,
                           int* __restrict__ deg, int Nn, int E) {
  const int e = blockIdx.x * blockDim.x + threadIdx.x;
  if (e < E) {
    atomicAdd(&deg[e1[e]], 1);
    atomicAdd(&deg[Nn + e0[e]], 1);
  }
}

__global__ __launch_bounds__(256) void scan_block(
    const int* __restrict__ deg, int* __restrict__ incl, int* __restrict__ bsum, int n) {
  __shared__ int buf[256];
  const int t = threadIdx.x;
  const int i = blockIdx.x * 256 + t;
  const int v = (i < n) ? deg[i] : 0;
  buf[t] = v;
  __syncthreads();
  for (int off = 1; off < 256; off <<= 1) {
    const int y = (t >= off) ? buf[t - off] : 0;
    __syncthreads();
    buf[t] += y;
    __syncthreads();
  }
  if (i < n) incl[i] = buf[t];
  if (t == 255) bsum[blockIdx.x] = buf[255];
}

__global__ __launch_bounds__(256) void scan_sums(
    int* __restrict__ bsum, int nb, int* __restrict__ row_total) {
  __shared__ int buf[256];
  const int t = threadIdx.x;
  const int v = (t < nb) ? bsum[t] : 0;
  buf[t] = v;
  __syncthreads();
  for (int off = 1; off < 256; off <<= 1) {
    const int y = (t >= off) ? buf[t - off] : 0;
    __syncthreads();
    buf[t] += y;
    __syncthreads();
  }
  if (t < nb) bsum[t] = buf[t] - v;  // exclusive
  if (t == 0) *row_total = buf[255];
}

__global__ __launch_bounds__(256) void scan_finalize(
    const int* __restrict__ incl, const int* __restrict__ deg,
    const int* __restrict__ bsum, int* __restrict__ row_start,
    int* __restrict__ cursor, int n) {
  const int i = blockIdx.x * 256 + threadIdx.x;
  if (i >= n) return;
  const int v = incl[i] - deg[i] + bsum[i >> 8];
  row_start[i] = v;
  cursor[i] = v;
}

__global__ void fill_csr2(const int* __restrict__ e1, const int* __restrict__ e0,
                          int* __restrict__ cursor, int* __restrict__ csr_s,
                          int Nn, int E) {
  const int e = blockIdx.x * blockDim.x + threadIdx.x;
  if (e >= E) return;
  const int d1 = e1[e];
  csr_s[atomicAdd(&cursor[d1], 1)] = e1[E + e];
  const int d0 = e0[e];
  csr_s[atomicAdd(&cursor[Nn + d0], 1)] = e0[E + e];
}

// ---------- GAT softmax + aggregate, one wave per dst ----------
__global__ __launch_bounds__(256) void gat_aggregate_w(
    ushort_t* __restrict__ featb, const ushort_t* __restrict__ hb,
    const float* __restrict__ sd, const float* __restrict__ ss,
    float* __restrict__ edge_e, const float* __restrict__ b_att_p,
    const float* __restrict__ gat_bias, const int* __restrict__ row_start,
    const int* __restrict__ csr_src, int Nn) {
  const int dst = blockIdx.x * 4 + (threadIdx.x >> 6);
  const int lane = threadIdx.x & 63;
  if (dst >= Nn) return;
  const int beg = row_start[dst];
  const int end = row_start[dst + 1];
  const int deg = end - beg;
  const float sdd = sd[dst];
  const float ba = b_att_p[0];
  float acc[8] = {};
  float inv;
  if (deg <= 64) {
    const int j0 = beg + lane;
    const bool valid = j0 < end;
    const float e = valid ? tanhf(sdd + ss[csr_src[j0]] + ba) : -1e30f;
    float m = e;
#pragma unroll
    for (int off = 32; off > 0; off >>= 1) m = fmaxf(m, __shfl_xor(m, off));
    float a = valid ? expf(e - m) : 0.f;
    float s = a;
#pragma unroll
    for (int off = 32; off > 0; off >>= 1) s += __shfl_xor(s, off);
    inv = (s > 0.f) ? 1.f / s : 0.f;
    int k = 0;
    for (; k + 1 < deg; k += 2) {
      const float w0 = __shfl(a, k) * inv;
      const float w1 = __shfl(a, k + 1) * inv;
      const int s0 = csr_src[beg + k];
      const int s1 = csr_src[beg + k + 1];
      const bf16x8 h0 = *reinterpret_cast<const bf16x8*>(&hb[(size_t)s0 * D + lane * 8]);
      const bf16x8 h1 = *reinterpret_cast<const bf16x8*>(&hb[(size_t)s1 * D + lane * 8]);
#pragma unroll
      for (int q = 0; q < 8; ++q)
        acc[q] += w0 * bf2f((ushort_t)h0[q]) + w1 * bf2f((ushort_t)h1[q]);
    }
    if (k < deg) {
      const float w = __shfl(a, k) * inv;
      const int s0 = csr_src[beg + k];
      const bf16x8 h0 = *reinterpret_cast<const bf16x8*>(&hb[(size_t)s0 * D + lane * 8]);
#pragma unroll
      for (int q = 0; q < 8; ++q) acc[q] += w * bf2f((ushort_t)h0[q]);
    }
  } else {
    float m = -1e30f;
    for (int j = beg + lane; j < end; j += 64) {
      const float e = tanhf(sdd + ss[csr_src[j]] + ba);
      edge_e[j] = e;
      m = fmaxf(m, e);
    }
#pragma unroll
    for (int off = 32; off > 0; off >>= 1) m = fmaxf(m, __shfl_xor(m, off));
    asm volatile("s_waitcnt vmcnt(0)" ::: "memory");
    float s = 0.f;
    for (int j = beg + lane; j < end; j += 64) {
      const float a2 = expf(edge_e[j] - m);
      edge_e[j] = a2;
      s += a2;
    }
#pragma unroll
    for (int off = 32; off > 0; off >>= 1) s += __shfl_xor(s, off);
    asm volatile("s_waitcnt vmcnt(0)" ::: "memory");
    inv = (s > 0.f) ? 1.f / s : 0.f;
    for (int j = beg; j < end; ++j) {
      const float w = edge_e[j] * inv;
      const int sidx = csr_src[j];
      const bf16x8 hv = *reinterpret_cast<const bf16x8*>(&hb[(size_t)sidx * D + lane * 8]);
#pragma unroll
      for (int q = 0; q < 8; ++q) acc[q] += w * bf2f((ushort_t)hv[q]);
    }
  }
  const size_t o = (size_t)dst * D + lane * 8;
  bf16x8 fv = *reinterpret_cast<const bf16x8*>(&featb[o]);
#pragma unroll
  for (int q = 0; q < 8; ++q) {
    const float f = (bf2f((ushort_t)fv[q]) + acc[q] + gat_bias[lane * 8 + q]) * 0.5f;
    fv[q] = (short)f2bf(f);
  }
  *reinterpret_cast<bf16x8*>(&featb[o]) = fv;
}

// ---------- fused head: gather -> Wp -> 2x(2x(GEMM,tanh,LN), res LN) -> logit
// 1024 threads (16 waves), one block per 16 batch rows; 2 n-tiles per wave.
__global__ __launch_bounds__(1024, 4) void head_fused(
    const ushort_t* __restrict__ featb, const int* __restrict__ tidx,
    const ushort_t* __restrict__ pWp, const float* __restrict__ bp,
    const ushort_t* __restrict__ pDW, const float* __restrict__ dnn_b,
    const float* __restrict__ dnn_g, const float* __restrict__ dnn_be,
    const float* __restrict__ res_g, const float* __restrict__ res_be,
    const float* __restrict__ Wc, const float* __restrict__ bc,
    float* __restrict__ out) {
  __shared__ __align__(16) ushort_t A_lds[16 * 512];
  __shared__ float lsum[16][16], lsq[16][16], meanv[16], rsv[16];
  const int tid = threadIdx.x;
  const int lane = tid & 63;
  const int wave = tid >> 6;      // 0..15
  const int nt0 = wave * 2;       // 2 n-tiles (32 cols) per wave
  const int c15 = lane & 15;
  const int rgrp = lane >> 4;

  // gather 16 target rows into swizzled A_lds (tid -> row=tid>>6, col8=tid&63)
  {
    const int row = tid >> 6, col8 = tid & 63;
    const int g = tidx[blockIdx.x * 16 + row];
    const bf16x8 v = *reinterpret_cast<const bf16x8*>(&featb[(size_t)g * D + col8 * 8]);
    *reinterpret_cast<bf16x8*>(&A_lds[row * 512 + (col8 ^ (row & 7)) * 8]) = v;
  }
  __syncthreads();

  // GEMM with depth-1 register prefetch of W fragments
  auto do_gemm = [&](const ushort_t* __restrict__ W, f32x4& a0, f32x4& a1) {
    a0 = f32x4{0.f, 0.f, 0.f, 0.f};
    a1 = f32x4{0.f, 0.f, 0.f, 0.f};
    bf16x8 c0 = *reinterpret_cast<const bf16x8*>(
        &W[(((size_t)nt0 * 16 + 0) << 9) + lane * 8]);
    bf16x8 c1 = *reinterpret_cast<const bf16x8*>(
        &W[(((size_t)(nt0 + 1) * 16 + 0) << 9) + lane * 8]);
#pragma unroll
    for (int kt = 0; kt < 16; ++kt) {
      bf16x8 n0 = c0, n1 = c1;
      if (kt < 15) {
        n0 = *reinterpret_cast<const bf16x8*>(
            &W[(((size_t)nt0 * 16 + kt + 1) << 9) + lane * 8]);
        n1 = *reinterpret_cast<const bf16x8*>(
            &W[(((size_t)(nt0 + 1) * 16 + kt + 1) << 9) + lane * 8]);
      }
      const int col8 = kt * 4 + rgrp;
      const bf16x8 af = *reinterpret_cast<const bf16x8*>(
          &A_lds[c15 * 512 + (col8 ^ (c15 & 7)) * 8]);
      a0 = __builtin_amdgcn_mfma_f32_16x16x32_bf16(af, c0, a0, 0, 0, 0);
      a1 = __builtin_amdgcn_mfma_f32_16x16x32_bf16(af, c1, a1, 0, 0, 0);
      c0 = n0;
      c1 = n1;
    }
  };

  auto block_ln = [&](f32x4& v0, f32x4& v1, const float* __restrict__ g,
                      const float* __restrict__ be) {
    float psum[4], psq[4];
#pragma unroll
    for (int r = 0; r < 4; ++r) {
      psum[r] = v0[r] + v1[r];
      psq[r] = v0[r] * v0[r] + v1[r] * v1[r];
    }
#pragma unroll
    for (int off = 8; off > 0; off >>= 1)
#pragma unroll
      for (int r = 0; r < 4; ++r) {
        psum[r] += __shfl_xor(psum[r], off);
        psq[r] += __shfl_xor(psq[r], off);
      }
    if (c15 == 0) {
#pragma unroll
      for (int r = 0; r < 4; ++r) {
        lsum[wave][rgrp * 4 + r] = psum[r];
        lsq[wave][rgrp * 4 + r] = psq[r];
      }
    }
    __syncthreads();
    if (tid < 16) {
      float s = 0.f, qq = 0.f;
#pragma unroll
      for (int w = 0; w < 16; ++w) { s += lsum[w][tid]; qq += lsq[w][tid]; }
      const float mean = s * (1.f / 512.f);
      const float var = qq * (1.f / 512.f) - mean * mean;
      meanv[tid] = mean;
      rsv[tid] = rsqrtf(var + 1e-5f);
    }
    __syncthreads();
    const int col0 = nt0 * 16 + c15;
    const int col1 = (nt0 + 1) * 16 + c15;
    const float g0 = g[col0], b0 = be[col0];
    const float g1 = g[col1], b1 = be[col1];
#pragma unroll
    for (int r = 0; r < 4; ++r) {
      const int row = rgrp * 4 + r;
      v0[r] = (v0[r] - meanv[row]) * rsv[row] * g0 + b0;
      v1[r] = (v1[r] - meanv[row]) * rsv[row] * g1 + b1;
    }
  };

  auto store_A = [&](const f32x4& v0, const f32x4& v1) {
    const int col0 = nt0 * 16 + c15;
    const int col1 = (nt0 + 1) * 16 + c15;
#pragma unroll
    for (int r = 0; r < 4; ++r) {
      const int row = rgrp * 4 + r;
      A_lds[row * 512 + (((col0 >> 3) ^ (row & 7)) << 3) + (col0 & 7)] = f2bf(v0[r]);
      A_lds[row * 512 + (((col1 >> 3) ^ (row & 7)) << 3) + (col1 & 7)] = f2bf(v1[r]);
    }
  };

  f32x4 sc0, sc1, acc0, acc1, ln0, ln1;

  // stage 0: sc = A @ Wp + bp
  do_gemm(pWp, acc0, acc1);
  {
    const float bv0 = bp[nt0 * 16 + c15];
    const float bv1 = bp[(nt0 + 1) * 16 + c15];
#pragma unroll
    for (int r = 0; r < 4; ++r) { sc0[r] = acc0[r] + bv0; sc1[r] = acc1[r] + bv1; }
  }
  __syncthreads();
  store_A(sc0, sc1);
  __syncthreads();

  for (int rb = 0; rb < 2; ++rb) {
    // dnn stage 2rb
    {
      const int st = rb * 2;
      do_gemm(pDW + (size_t)st * D * D, acc0, acc1);
      const float bv0 = dnn_b[st * D + nt0 * 16 + c15];
      const float bv1 = dnn_b[st * D + (nt0 + 1) * 16 + c15];
#pragma unroll
      for (int r = 0; r < 4; ++r) {
        acc0[r] = tanhf(acc0[r] + bv0);
        acc1[r] = tanhf(acc1[r] + bv1);
      }
      block_ln(acc0, acc1, dnn_g + st * D, dnn_be + st * D);
      store_A(acc0, acc1);
      __syncthreads();
    }
    // dnn stage 2rb+1
    {
      const int st = rb * 2 + 1;
      do_gemm(pDW + (size_t)st * D * D, ln0, ln1);
      const float bv0 = dnn_b[st * D + nt0 * 16 + c15];
      const float bv1 = dnn_b[st * D + (nt0 + 1) * 16 + c15];
#pragma unroll
      for (int r = 0; r < 4; ++r) {
        ln0[r] = tanhf(ln0[r] + bv0);
        ln1[r] = tanhf(ln1[r] + bv1);
      }
      block_ln(ln0, ln1, dnn_g + st * D, dnn_be + st * D);
    }
    // residual: sc = LN(tanh(sc + ln))
#pragma unroll
    for (int r = 0; r < 4; ++r) {
      acc0[r] = tanhf(sc0[r] + ln0[r]);
      acc1[r] = tanhf(sc1[r] + ln1[r]);
    }
    block_ln(acc0, acc1, res_g + rb * D, res_be + rb * D);
    sc0 = acc0;
    sc1 = acc1;
    if (rb == 0) {
      store_A(sc0, sc1);
      __syncthreads();
    }
  }

  // final logit + sigmoid
  float pr[4];
  {
    const float w0 = Wc[nt0 * 16 + c15];
    const float w1 = Wc[(nt0 + 1) * 16 + c15];
#pragma unroll
    for (int r = 0; r < 4; ++r) pr[r] = sc0[r] * w0 + sc1[r] * w1;
  }
#pragma unroll
  for (int off = 8; off > 0; off >>= 1)
#pragma unroll
    for (int r = 0; r < 4; ++r) pr[r] += __shfl_xor(pr[r], off);
  __syncthreads();
  if (c15 == 0) {
#pragma unroll
    for (int r = 0; r < 4; ++r) lsum[wave][rgrp * 4 + r] = pr[r];
  }
  __syncthreads();
  if (tid < 16) {
    float s = 0.f;
#pragma unroll
    for (int w = 0; w < 16; ++w) s += lsum[w][tid];
    out[blockIdx.x * 16 + tid] = 1.f / (1.f + expf(-(s + bc[0])));
  }
}

extern "C" void kernel_launch(void* const* d_in, const int* in_sizes, int n_in,
                              void* d_out, int out_size, void* d_ws, size_t ws_size,
                              hipStream_t stream) {
  (void)n_in; (void)out_size; (void)ws_size;
  const float* node_feat = (const float*)d_in[0];
  const int* edge0 = (const int*)d_in[1];
  const int* edge1 = (const int*)d_in[2];
  const int* tidx = (const int*)d_in[3];
  const float* Wt = (const float*)d_in[4];
  const float* bt = (const float*)d_in[5];
  const float* Wf = (const float*)d_in[6];
  const float* bfp = (const float*)d_in[7];
  const float* w_att = (const float*)d_in[8];
  const float* b_att = (const float*)d_in[9];
  const float* gat_bias = (const float*)d_in[10];
  const float* Wp = (const float*)d_in[11];
  const float* bp = (const float*)d_in[12];
  const float* dnn_W = (const float*)d_in[13];
  const float* dnn_b = (const float*)d_in[14];
  const float* dnn_g = (const float*)d_in[15];
  const float* dnn_be = (const float*)d_in[16];
  const float* res_g = (const float*)d_in[17];
  const float* res_be = (const float*)d_in[18];
  const float* Wc = (const float*)d_in[19];
  const float* bc = (const float*)d_in[20];
  float* out = (float*)d_out;

  const int Nn = in_sizes[0] / D;   // 30000
  const int E = in_sizes[1] / 2;    // 300000
  const int B = in_sizes[3];        // 4096
  const int K_IN = in_sizes[4] / D; // 512
  const int Mp = (Nn + 127) / 128 * 128;
  const int N2 = 2 * Nn;

  char* p = (char*)d_ws;
  auto alloc = [&](size_t bytes) -> char* {
    char* r = p;
    p += (bytes + 255) & ~(size_t)255;
    return r;
  };
  ushort_t* featb = (ushort_t*)alloc((size_t)Mp * D * 2);
  ushort_t* hb = (ushort_t*)alloc((size_t)Mp * D * 2);  // also nfb pre-hop
  float* sd = (float*)alloc((size_t)Nn * 4);
  float* ss = (float*)alloc((size_t)Nn * 4);
  int* deg = (int*)alloc((size_t)N2 * 4);
  int* incl = (int*)alloc((size_t)N2 * 4);
  int* bsum = (int*)alloc(256 * 4);
  int* cursor = (int*)alloc((size_t)N2 * 4);
  int* row_start = (int*)alloc((size_t)(N2 + 1) * 4);
  int* csr_s = (int*)alloc((size_t)2 * E * 4);
  float* edge_e = (float*)alloc((size_t)2 * E * 4);
  ushort_t* pWt = (ushort_t*)alloc((size_t)K_IN * D * 2);
  ushort_t* pWf = (ushort_t*)alloc((size_t)D * D * 2);
  ushort_t* pWp = (ushort_t*)alloc((size_t)D * D * 2);
  ushort_t* pDWall = (ushort_t*)alloc((size_t)4 * D * D * 2);

  dim3 blk(256);
  const int nb2 = (N2 + 255) / 256;
  const int nw4 = (Nn + 3) / 4;

  // ---- one-time packs / converts ----
  {
    pack_weight<<<(K_IN * D + 255) / 256, blk, 0, stream>>>(Wt, pWt, K_IN, D, 1);
    pack_weight<<<(D * D + 255) / 256, blk, 0, stream>>>(Wf, pWf, D, D, 1);
    pack_weight<<<(D * D + 255) / 256, blk, 0, stream>>>(Wp, pWp, D, D, 1);
    pack_weight<<<(4 * D * D + 255) / 256, blk, 0, stream>>>(dnn_W, pDWall, D, D, 4);
    conv_bf16_pad<<<((size_t)Mp * K_IN / 4 + 255) / 256, blk, 0, stream>>>(
        node_feat, hb /*nfb*/, Nn, Mp, K_IN);
  }

  // ---- CSR for both hops (hop1 -> segment 0, hop0 -> segment 1) ----
  hipMemsetAsync(deg, 0, (size_t)N2 * 4, stream);
  count_deg2<<<(E + 255) / 256, blk, 0, stream>>>(edge1, edge0, deg, Nn, E);
  scan_block<<<nb2, blk, 0, stream>>>(deg, incl, bsum, N2);
  scan_sums<<<1, blk, 0, stream>>>(bsum, nb2, &row_start[N2]);
  scan_finalize<<<nb2, blk, 0, stream>>>(incl, deg, bsum, row_start, cursor, N2);
  fill_csr2<<<(E + 255) / 256, blk, 0, stream>>>(edge1, edge0, cursor, csr_s, Nn, E);

  // ---- feat = node_feat @ Wt + bt ----
  gemm_mfma<<<dim3(4 * (Mp / 128)), blk, 0, stream>>>(hb, pWt, bt, featb, D, K_IN);

  // ---- two GAT hops ----
  for (int hp = 0; hp < 2; ++hp) {
    gemm_mfma<<<dim3(4 * (Mp / 128)), blk, 0, stream>>>(featb, pWf, bfp, hb, D, D);
    rowdot2_w<<<nw4, blk, 0, stream>>>(hb, w_att, sd, ss, Nn);
    gat_aggregate_w<<<nw4, blk, 0, stream>>>(featb, hb, sd, ss, edge_e, b_att,
                                             gat_bias, row_start + hp * Nn, csr_s, Nn);
  }

  // ---- fused head ----
  head_fused<<<B / 16, dim3(1024), 0, stream>>>(
      featb, tidx, pWp, bp, pDWall, dnn_b, dnn_g, dnn_be, res_g, res_be,
      Wc, bc, out);
}

// Round 7
// 355.363 us; speedup vs baseline: 1.4749x; 1.0068x over previous
//
#include <hip/hip_runtime.h>

#define D 512
typedef unsigned short ushort_t;
typedef __attribute__((ext_vector_type(8))) short bf16x8;
typedef __attribute__((ext_vector_type(4))) float f32x4;

static __device__ __forceinline__ ushort_t f2bf(float f) {
  unsigned u = __float_as_uint(f);
  u += 0x7fffu + ((u >> 16) & 1u);  // RNE
  return (ushort_t)(u >> 16);
}
static __device__ __forceinline__ float bf2f(ushort_t h) {
  return __uint_as_float(((unsigned)h) << 16);
}

static __device__ __forceinline__ void gld_lds16(const void* g, void* lds) {
  __builtin_amdgcn_global_load_lds(
      (const __attribute__((address_space(1))) unsigned int*)g,
      (__attribute__((address_space(3))) unsigned int*)lds, 16, 0, 0);
}

// ---------- weight pack: nmat x W[K][N] fp32 -> fragment-ready bf16 ----------
__global__ __launch_bounds__(256) void pack_weight(
    const float* __restrict__ W, ushort_t* __restrict__ out, int K, int N, int nmat) {
  int i = blockIdx.x * 256 + threadIdx.x;
  const int per = K * N;
  if (i >= per * nmat) return;
  const int mat = i / per;
  const int r = i - mat * per;
  const int k = r / N, n = r - k * N;
  const int nt = n >> 4, col = n & 15, kt = k >> 5, kg = (k >> 3) & 3, j = k & 7;
  out[(size_t)mat * per + (((size_t)nt * (K >> 5) + kt) << 9) + ((kg << 4) + col) * 8 + j] =
      f2bf(W[(size_t)mat * per + r]);
}

// ---------- fp32 -> bf16 row-major with row padding ----------
__global__ __launch_bounds__(256) void conv_bf16_pad(
    const float* __restrict__ in, ushort_t* __restrict__ out, int M, int Mp, int K) {
  const size_t i4 = ((size_t)blockIdx.x * 256 + threadIdx.x) * 4;
  if (i4 >= (size_t)Mp * K) return;
  const int row = (int)(i4 / K);
  ushort4 o;
  if (row < M) {
    const float4 v = *reinterpret_cast<const float4*>(&in[i4]);
    o.x = f2bf(v.x); o.y = f2bf(v.y); o.z = f2bf(v.z); o.w = f2bf(v.w);
  } else {
    o.x = o.y = o.z = o.w = 0;
  }
  *reinterpret_cast<ushort4*>(&out[i4]) = o;
}

// ---------- node MFMA GEMM, 2-phase double-buffered LDS pipeline ----------
// 128x128 tile, 4 waves, BK=32, XCD-bijective-swizzled 1D grid (NBX=4 cols).
__global__ __launch_bounds__(256) void gemm_mfma(
    const ushort_t* __restrict__ A, const ushort_t* __restrict__ Bp,
    const float* __restrict__ bias, ushort_t* __restrict__ C16, int N, int K) {
  __shared__ __align__(16) ushort_t As[2][8 * 512];
  __shared__ __align__(16) ushort_t Bs[2][8 * 512];
  const int nwg = gridDim.x;
  const int q = nwg >> 3, rm = nwg & 7;
  const int xcd = blockIdx.x & 7, kk = blockIdx.x >> 3;
  const int lin = (xcd < rm ? xcd * (q + 1) : rm * (q + 1) + (xcd - rm) * q) + kk;
  const int m0 = (lin >> 2) * 128;
  const int n0 = (lin & 3) * 128;
  const int tid = threadIdx.x;
  const int lane = tid & 63;
  const int wid = tid >> 6;
  const int wm = wid >> 1, wn = wid & 1;
  const int arow = lane & 15;
  const int akoff = (lane >> 4) * 8;
  const int kt32 = K >> 5;
  f32x4 acc[4][4] = {};

  auto stage = [&](int kt, int b) {
    const int k0 = kt * 32;
    gld_lds16(&A[(size_t)(m0 + (wid * 2 + 0) * 16 + arow) * K + k0 + akoff],
              &As[b][(wid * 2 + 0) * 512]);
    gld_lds16(&A[(size_t)(m0 + (wid * 2 + 1) * 16 + arow) * K + k0 + akoff],
              &As[b][(wid * 2 + 1) * 512]);
    gld_lds16(&Bp[(((size_t)(n0 / 16 + wid * 2 + 0) * kt32 + kt) << 9) + lane * 8],
              &Bs[b][(wid * 2 + 0) * 512]);
    gld_lds16(&Bp[(((size_t)(n0 / 16 + wid * 2 + 1) * kt32 + kt) << 9) + lane * 8],
              &Bs[b][(wid * 2 + 1) * 512]);
  };

  stage(0, 0);
  __syncthreads();  // compiler drains vmcnt before s_barrier
  int cur = 0;
  for (int t = 0; t < kt32; ++t) {
    if (t + 1 < kt32) stage(t + 1, cur ^ 1);  // prefetch next tile
    bf16x8 af[4], bfr[4];
#pragma unroll
    for (int mi = 0; mi < 4; ++mi)
      af[mi] = *reinterpret_cast<const bf16x8*>(&As[cur][(wm * 4 + mi) * 512 + lane * 8]);
#pragma unroll
    for (int ni = 0; ni < 4; ++ni)
      bfr[ni] = *reinterpret_cast<const bf16x8*>(&Bs[cur][(wn * 4 + ni) * 512 + lane * 8]);
#pragma unroll
    for (int mi = 0; mi < 4; ++mi)
#pragma unroll
      for (int ni = 0; ni < 4; ++ni)
        acc[mi][ni] = __builtin_amdgcn_mfma_f32_16x16x32_bf16(af[mi], bfr[ni], acc[mi][ni], 0, 0, 0);
    __syncthreads();  // drains prefetch vmcnt + fences buf reuse
    cur ^= 1;
  }
#pragma unroll
  for (int mi = 0; mi < 4; ++mi) {
    const int row = m0 + wm * 64 + mi * 16 + ((lane >> 4) << 2);
#pragma unroll
    for (int ni = 0; ni < 4; ++ni) {
      const int col = n0 + wn * 64 + ni * 16 + (lane & 15);
      const float bv = bias[col];
#pragma unroll
      for (int r = 0; r < 4; ++r)
        C16[(size_t)(row + r) * N + col] = f2bf(acc[mi][ni][r] + bv);
    }
  }
}

// ---------- per-row double dot, one wave per row ----------
__global__ __launch_bounds__(256) void rowdot2_w(
    const ushort_t* __restrict__ hb, const float* __restrict__ w_att,
    float* __restrict__ sd, float* __restrict__ ss, int Nn) {
  const int r = blockIdx.x * 4 + (threadIdx.x >> 6);
  const int lane = threadIdx.x & 63;
  if (r >= Nn) return;
  const bf16x8 hv = *reinterpret_cast<const bf16x8*>(&hb[(size_t)r * D + lane * 8]);
  float d0 = 0.f, d1 = 0.f;
#pragma unroll
  for (int q = 0; q < 8; ++q) {
    const float v = bf2f((ushort_t)hv[q]);
    d0 += v * w_att[lane * 8 + q];
    d1 += v * w_att[D + lane * 8 + q];
  }
#pragma unroll
  for (int off = 32; off > 0; off >>= 1) {
    d0 += __shfl_xor(d0, off);
    d1 += __shfl_xor(d1, off);
  }
  if (lane == 0) { sd[r] = d0; ss[r] = d1; }
}

// ---------- CSR build (both hops, concatenated segment space) ----------
__global__ void count_deg2(const int* __restrict__ e1, const int* __restrict__ e0,
                           int* __restrict__ deg, int Nn, int E) {
  const int e = blockIdx.x * blockDim.x + threadIdx.x;
  if (e < E) {
    atomicAdd(&deg[e1[e]], 1);
    atomicAdd(&deg[Nn + e0[e]], 1);
  }
}

__global__ __launch_bounds__(256) void scan_block(
    const int* __restrict__ deg, int* __restrict__ incl, int* __restrict__ bsum, int n) {
  __shared__ int buf[256];
  const int t = threadIdx.x;
  const int i = blockIdx.x * 256 + t;
  const int v = (i < n) ? deg[i] : 0;
  buf[t] = v;
  __syncthreads();
  for (int off = 1; off < 256; off <<= 1) {
    const int y = (t >= off) ? buf[t - off] : 0;
    __syncthreads();
    buf[t] += y;
    __syncthreads();
  }
  if (i < n) incl[i] = buf[t];
  if (t == 255) bsum[blockIdx.x] = buf[255];
}

__global__ __launch_bounds__(256) void scan_sums(
    int* __restrict__ bsum, int nb, int* __restrict__ row_total) {
  __shared__ int buf[256];
  const int t = threadIdx.x;
  const int v = (t < nb) ? bsum[t] : 0;
  buf[t] = v;
  __syncthreads();
  for (int off = 1; off < 256; off <<= 1) {
    const int y = (t >= off) ? buf[t - off] : 0;
    __syncthreads();
    buf[t] += y;
    __syncthreads();
  }
  if (t < nb) bsum[t] = buf[t] - v;  // exclusive
  if (t == 0) *row_total = buf[255];
}

__global__ __launch_bounds__(256) void scan_finalize(
    const int* __restrict__ incl, const int* __restrict__ deg,
    const int* __restrict__ bsum, int* __restrict__ row_start,
    int* __restrict__ cursor, int n) {
  const int i = blockIdx.x * 256 + threadIdx.x;
  if (i >= n) return;
  const int v = incl[i] - deg[i] + bsum[i >> 8];
  row_start[i] = v;
  cursor[i] = v;
}

__global__ void fill_csr2(const int* __restrict__ e1, const int* __restrict__ e0,
                          int* __restrict__ cursor, int* __restrict__ csr_s,
                          int Nn, int E) {
  const int e = blockIdx.x * blockDim.x + threadIdx.x;
  if (e >= E) return;
  const int d1 = e1[e];
  csr_s[atomicAdd(&cursor[d1], 1)] = e1[E + e];
  const int d0 = e0[e];
  csr_s[atomicAdd(&cursor[Nn + d0], 1)] = e0[E + e];
}

// ---------- GAT softmax + aggregate, one wave per dst ----------
// src indices live in lane registers; phase 3 broadcasts via shfl, 4x unroll.
__global__ __launch_bounds__(256) void gat_aggregate_w(
    ushort_t* __restrict__ featb, const ushort_t* __restrict__ hb,
    const float* __restrict__ sd, const float* __restrict__ ss,
    float* __restrict__ edge_e, const float* __restrict__ b_att_p,
    const float* __restrict__ gat_bias, const int* __restrict__ row_start,
    const int* __restrict__ csr_src, int Nn) {
  const int dst = blockIdx.x * 4 + (threadIdx.x >> 6);
  const int lane = threadIdx.x & 63;
  if (dst >= Nn) return;
  const int beg = row_start[dst];
  const int end = row_start[dst + 1];
  const int deg = end - beg;
  const float sdd = sd[dst];
  const float ba = b_att_p[0];
  const size_t o = (size_t)dst * D + lane * 8;
  bf16x8 fv = *reinterpret_cast<const bf16x8*>(&featb[o]);  // hoisted RMW load
  float acc[8] = {};
  if (deg <= 64) {
    const int j0 = beg + lane;
    const bool valid = j0 < end;
    const int slane = valid ? csr_src[j0] : 0;
    const float e = valid ? tanhf(sdd + ss[slane] + ba) : -1e30f;
    float m = e;
#pragma unroll
    for (int off = 32; off > 0; off >>= 1) m = fmaxf(m, __shfl_xor(m, off));
    const float a = valid ? expf(e - m) : 0.f;
    float s = a;
#pragma unroll
    for (int off = 32; off > 0; off >>= 1) s += __shfl_xor(s, off);
    const float w = a * ((s > 0.f) ? 1.f / s : 0.f);  // per-lane alpha
    int k = 0;
    for (; k + 3 < deg; k += 4) {
      const float w0 = __shfl(w, k), w1 = __shfl(w, k + 1);
      const float w2 = __shfl(w, k + 2), w3 = __shfl(w, k + 3);
      const int s0 = __shfl(slane, k), s1 = __shfl(slane, k + 1);
      const int s2 = __shfl(slane, k + 2), s3 = __shfl(slane, k + 3);
      const bf16x8 h0 = *reinterpret_cast<const bf16x8*>(&hb[(size_t)s0 * D + lane * 8]);
      const bf16x8 h1 = *reinterpret_cast<const bf16x8*>(&hb[(size_t)s1 * D + lane * 8]);
      const bf16x8 h2 = *reinterpret_cast<const bf16x8*>(&hb[(size_t)s2 * D + lane * 8]);
      const bf16x8 h3 = *reinterpret_cast<const bf16x8*>(&hb[(size_t)s3 * D + lane * 8]);
#pragma unroll
      for (int qq = 0; qq < 8; ++qq)
        acc[qq] += w0 * bf2f((ushort_t)h0[qq]) + w1 * bf2f((ushort_t)h1[qq]) +
                   w2 * bf2f((ushort_t)h2[qq]) + w3 * bf2f((ushort_t)h3[qq]);
    }
    for (; k < deg; ++k) {
      const float wk = __shfl(w, k);
      const int sk = __shfl(slane, k);
      const bf16x8 h0 = *reinterpret_cast<const bf16x8*>(&hb[(size_t)sk * D + lane * 8]);
#pragma unroll
      for (int qq = 0; qq < 8; ++qq) acc[qq] += wk * bf2f((ushort_t)h0[qq]);
    }
  } else {
    // spill path via edge_e (rare)
    float m = -1e30f;
    for (int j = beg + lane; j < end; j += 64) {
      const float e = tanhf(sdd + ss[csr_src[j]] + ba);
      edge_e[j] = e;
      m = fmaxf(m, e);
    }
#pragma unroll
    for (int off = 32; off > 0; off >>= 1) m = fmaxf(m, __shfl_xor(m, off));
    asm volatile("s_waitcnt vmcnt(0)" ::: "memory");
    float s = 0.f;
    for (int j = beg + lane; j < end; j += 64) {
      const float a2 = expf(edge_e[j] - m);
      edge_e[j] = a2;
      s += a2;
    }
#pragma unroll
    for (int off = 32; off > 0; off >>= 1) s += __shfl_xor(s, off);
    asm volatile("s_waitcnt vmcnt(0)" ::: "memory");
    const float inv = (s > 0.f) ? 1.f / s : 0.f;
    for (int j = beg; j < end; ++j) {
      const float w = edge_e[j] * inv;
      const int sidx = csr_src[j];
      const bf16x8 hv = *reinterpret_cast<const bf16x8*>(&hb[(size_t)sidx * D + lane * 8]);
#pragma unroll
      for (int qq = 0; qq < 8; ++qq) acc[qq] += w * bf2f((ushort_t)hv[qq]);
    }
  }
#pragma unroll
  for (int q = 0; q < 8; ++q) {
    const float f = (bf2f((ushort_t)fv[q]) + acc[q] + gat_bias[lane * 8 + q]) * 0.5f;
    fv[q] = (short)f2bf(f);
  }
  *reinterpret_cast<bf16x8*>(&featb[o]) = fv;
}

// ---------- fused head: gather -> Wp -> 2x(2x(GEMM,tanh,LN), res LN) -> logit
// 1024 threads (16 waves), one block per 16 batch rows; 2 n-tiles per wave.
__global__ __launch_bounds__(1024, 4) void head_fused(
    const ushort_t* __restrict__ featb, const int* __restrict__ tidx,
    const ushort_t* __restrict__ pWp, const float* __restrict__ bp,
    const ushort_t* __restrict__ pDW, const float* __restrict__ dnn_b,
    const float* __restrict__ dnn_g, const float* __restrict__ dnn_be,
    const float* __restrict__ res_g, const float* __restrict__ res_be,
    const float* __restrict__ Wc, const float* __restrict__ bc,
    float* __restrict__ out) {
  __shared__ __align__(16) ushort_t A_lds[16 * 512];
  __shared__ float lsum[16][16], lsq[16][16], meanv[16], rsv[16];
  const int tid = threadIdx.x;
  const int lane = tid & 63;
  const int wave = tid >> 6;      // 0..15
  const int nt0 = wave * 2;       // 2 n-tiles (32 cols) per wave
  const int c15 = lane & 15;
  const int rgrp = lane >> 4;

  {
    const int row = tid >> 6, col8 = tid & 63;
    const int g = tidx[blockIdx.x * 16 + row];
    const bf16x8 v = *reinterpret_cast<const bf16x8*>(&featb[(size_t)g * D + col8 * 8]);
    *reinterpret_cast<bf16x8*>(&A_lds[row * 512 + (col8 ^ (row & 7)) * 8]) = v;
  }
  __syncthreads();

  auto do_gemm = [&](const ushort_t* __restrict__ W, f32x4& a0, f32x4& a1) {
    a0 = f32x4{0.f, 0.f, 0.f, 0.f};
    a1 = f32x4{0.f, 0.f, 0.f, 0.f};
    bf16x8 c0 = *reinterpret_cast<const bf16x8*>(
        &W[(((size_t)nt0 * 16 + 0) << 9) + lane * 8]);
    bf16x8 c1 = *reinterpret_cast<const bf16x8*>(
        &W[(((size_t)(nt0 + 1) * 16 + 0) << 9) + lane * 8]);
#pragma unroll
    for (int kt = 0; kt < 16; ++kt) {
      bf16x8 n0 = c0, n1 = c1;
      if (kt < 15) {
        n0 = *reinterpret_cast<const bf16x8*>(
            &W[(((size_t)nt0 * 16 + kt + 1) << 9) + lane * 8]);
        n1 = *reinterpret_cast<const bf16x8*>(
            &W[(((size_t)(nt0 + 1) * 16 + kt + 1) << 9) + lane * 8]);
      }
      const int col8 = kt * 4 + rgrp;
      const bf16x8 af = *reinterpret_cast<const bf16x8*>(
          &A_lds[c15 * 512 + (col8 ^ (c15 & 7)) * 8]);
      a0 = __builtin_amdgcn_mfma_f32_16x16x32_bf16(af, c0, a0, 0, 0, 0);
      a1 = __builtin_amdgcn_mfma_f32_16x16x32_bf16(af, c1, a1, 0, 0, 0);
      c0 = n0;
      c1 = n1;
    }
  };

  auto block_ln = [&](f32x4& v0, f32x4& v1, const float* __restrict__ g,
                      const float* __restrict__ be) {
    float psum[4], psq[4];
#pragma unroll
    for (int r = 0; r < 4; ++r) {
      psum[r] = v0[r] + v1[r];
      psq[r] = v0[r] * v0[r] + v1[r] * v1[r];
    }
#pragma unroll
    for (int off = 8; off > 0; off >>= 1)
#pragma unroll
      for (int r = 0; r < 4; ++r) {
        psum[r] += __shfl_xor(psum[r], off);
        psq[r] += __shfl_xor(psq[r], off);
      }
    if (c15 == 0) {
#pragma unroll
      for (int r = 0; r < 4; ++r) {
        lsum[wave][rgrp * 4 + r] = psum[r];
        lsq[wave][rgrp * 4 + r] = psq[r];
      }
    }
    __syncthreads();
    if (tid < 16) {
      float s = 0.f, qq = 0.f;
#pragma unroll
      for (int w = 0; w < 16; ++w) { s += lsum[w][tid]; qq += lsq[w][tid]; }
      const float mean = s * (1.f / 512.f);
      const float var = qq * (1.f / 512.f) - mean * mean;
      meanv[tid] = mean;
      rsv[tid] = rsqrtf(var + 1e-5f);
    }
    __syncthreads();
    const int col0 = nt0 * 16 + c15;
    const int col1 = (nt0 + 1) * 16 + c15;
    const float g0 = g[col0], b0 = be[col0];
    const float g1 = g[col1], b1 = be[col1];
#pragma unroll
    for (int r = 0; r < 4; ++r) {
      const int row = rgrp * 4 + r;
      v0[r] = (v0[r] - meanv[row]) * rsv[row] * g0 + b0;
      v1[r] = (v1[r] - meanv[row]) * rsv[row] * g1 + b1;
    }
  };

  auto store_A = [&](const f32x4& v0, const f32x4& v1) {
    const int col0 = nt0 * 16 + c15;
    const int col1 = (nt0 + 1) * 16 + c15;
#pragma unroll
    for (int r = 0; r < 4; ++r) {
      const int row = rgrp * 4 + r;
      A_lds[row * 512 + (((col0 >> 3) ^ (row & 7)) << 3) + (col0 & 7)] = f2bf(v0[r]);
      A_lds[row * 512 + (((col1 >> 3) ^ (row & 7)) << 3) + (col1 & 7)] = f2bf(v1[r]);
    }
  };

  f32x4 sc0, sc1, acc0, acc1, ln0, ln1;

  do_gemm(pWp, acc0, acc1);
  {
    const float bv0 = bp[nt0 * 16 + c15];
    const float bv1 = bp[(nt0 + 1) * 16 + c15];
#pragma unroll
    for (int r = 0; r < 4; ++r) { sc0[r] = acc0[r] + bv0; sc1[r] = acc1[r] + bv1; }
  }
  __syncthreads();
  store_A(sc0, sc1);
  __syncthreads();

  for (int rb = 0; rb < 2; ++rb) {
    {
      const int st = rb * 2;
      do_gemm(pDW + (size_t)st * D * D, acc0, acc1);
      const float bv0 = dnn_b[st * D + nt0 * 16 + c15];
      const float bv1 = dnn_b[st * D + (nt0 + 1) * 16 + c15];
#pragma unroll
      for (int r = 0; r < 4; ++r) {
        acc0[r] = tanhf(acc0[r] + bv0);
        acc1[r] = tanhf(acc1[r] + bv1);
      }
      block_ln(acc0, acc1, dnn_g + st * D, dnn_be + st * D);
      store_A(acc0, acc1);
      __syncthreads();
    }
    {
      const int st = rb * 2 + 1;
      do_gemm(pDW + (size_t)st * D * D, ln0, ln1);
      const float bv0 = dnn_b[st * D + nt0 * 16 + c15];
      const float bv1 = dnn_b[st * D + (nt0 + 1) * 16 + c15];
#pragma unroll
      for (int r = 0; r < 4; ++r) {
        ln0[r] = tanhf(ln0[r] + bv0);
        ln1[r] = tanhf(ln1[r] + bv1);
      }
      block_ln(ln0, ln1, dnn_g + st * D, dnn_be + st * D);
    }
#pragma unroll
    for (int r = 0; r < 4; ++r) {
      acc0[r] = tanhf(sc0[r] + ln0[r]);
      acc1[r] = tanhf(sc1[r] + ln1[r]);
    }
    block_ln(acc0, acc1, res_g + rb * D, res_be + rb * D);
    sc0 = acc0;
    sc1 = acc1;
    if (rb == 0) {
      store_A(sc0, sc1);
      __syncthreads();
    }
  }

  float pr[4];
  {
    const float w0 = Wc[nt0 * 16 + c15];
    const float w1 = Wc[(nt0 + 1) * 16 + c15];
#pragma unroll
    for (int r = 0; r < 4; ++r) pr[r] = sc0[r] * w0 + sc1[r] * w1;
  }
#pragma unroll
  for (int off = 8; off > 0; off >>= 1)
#pragma unroll
    for (int r = 0; r < 4; ++r) pr[r] += __shfl_xor(pr[r], off);
  __syncthreads();
  if (c15 == 0) {
#pragma unroll
    for (int r = 0; r < 4; ++r) lsum[wave][rgrp * 4 + r] = pr[r];
  }
  __syncthreads();
  if (tid < 16) {
    float s = 0.f;
#pragma unroll
    for (int w = 0; w < 16; ++w) s += lsum[w][tid];
    out[blockIdx.x * 16 + tid] = 1.f / (1.f + expf(-(s + bc[0])));
  }
}

extern "C" void kernel_launch(void* const* d_in, const int* in_sizes, int n_in,
                              void* d_out, int out_size, void* d_ws, size_t ws_size,
                              hipStream_t stream) {
  (void)n_in; (void)out_size; (void)ws_size;
  const float* node_feat = (const float*)d_in[0];
  const int* edge0 = (const int*)d_in[1];
  const int* edge1 = (const int*)d_in[2];
  const int* tidx = (const int*)d_in[3];
  const float* Wt = (const float*)d_in[4];
  const float* bt = (const float*)d_in[5];
  const float* Wf = (const float*)d_in[6];
  const float* bfp = (const float*)d_in[7];
  const float* w_att = (const float*)d_in[8];
  const float* b_att = (const float*)d_in[9];
  const float* gat_bias = (const float*)d_in[10];
  const float* Wp = (const float*)d_in[11];
  const float* bp = (const float*)d_in[12];
  const float* dnn_W = (const float*)d_in[13];
  const float* dnn_b = (const float*)d_in[14];
  const float* dnn_g = (const float*)d_in[15];
  const float* dnn_be = (const float*)d_in[16];
  const float* res_g = (const float*)d_in[17];
  const float* res_be = (const float*)d_in[18];
  const float* Wc = (const float*)d_in[19];
  const float* bc = (const float*)d_in[20];
  float* out = (float*)d_out;

  const int Nn = in_sizes[0] / D;   // 30000
  const int E = in_sizes[1] / 2;    // 300000
  const int B = in_sizes[3];        // 4096
  const int K_IN = in_sizes[4] / D; // 512
  const int Mp = (Nn + 127) / 128 * 128;
  const int N2 = 2 * Nn;

  char* p = (char*)d_ws;
  auto alloc = [&](size_t bytes) -> char* {
    char* r = p;
    p += (bytes + 255) & ~(size_t)255;
    return r;
  };
  ushort_t* featb = (ushort_t*)alloc((size_t)Mp * D * 2);
  ushort_t* hb = (ushort_t*)alloc((size_t)Mp * D * 2);  // also nfb pre-hop
  float* sd = (float*)alloc((size_t)Nn * 4);
  float* ss = (float*)alloc((size_t)Nn * 4);
  int* deg = (int*)alloc((size_t)N2 * 4);
  int* incl = (int*)alloc((size_t)N2 * 4);
  int* bsum = (int*)alloc(256 * 4);
  int* cursor = (int*)alloc((size_t)N2 * 4);
  int* row_start = (int*)alloc((size_t)(N2 + 1) * 4);
  int* csr_s = (int*)alloc((size_t)2 * E * 4);
  float* edge_e = (float*)alloc((size_t)2 * E * 4);
  ushort_t* pWt = (ushort_t*)alloc((size_t)K_IN * D * 2);
  ushort_t* pWf = (ushort_t*)alloc((size_t)D * D * 2);
  ushort_t* pWp = (ushort_t*)alloc((size_t)D * D * 2);
  ushort_t* pDWall = (ushort_t*)alloc((size_t)4 * D * D * 2);

  dim3 blk(256);
  const int nb2 = (N2 + 255) / 256;
  const int nw4 = (Nn + 3) / 4;

  // ---- one-time packs / converts ----
  {
    pack_weight<<<(K_IN * D + 255) / 256, blk, 0, stream>>>(Wt, pWt, K_IN, D, 1);
    pack_weight<<<(D * D + 255) / 256, blk, 0, stream>>>(Wf, pWf, D, D, 1);
    pack_weight<<<(D * D + 255) / 256, blk, 0, stream>>>(Wp, pWp, D, D, 1);
    pack_weight<<<(4 * D * D + 255) / 256, blk, 0, stream>>>(dnn_W, pDWall, D, D, 4);
    conv_bf16_pad<<<((size_t)Mp * K_IN / 4 + 255) / 256, blk, 0, stream>>>(
        node_feat, hb /*nfb*/, Nn, Mp, K_IN);
  }

  // ---- CSR for both hops (hop1 -> segment 0, hop0 -> segment 1) ----
  hipMemsetAsync(deg, 0, (size_t)N2 * 4, stream);
  count_deg2<<<(E + 255) / 256, blk, 0, stream>>>(edge1, edge0, deg, Nn, E);
  scan_block<<<nb2, blk, 0, stream>>>(deg, incl, bsum, N2);
  scan_sums<<<1, blk, 0, stream>>>(bsum, nb2, &row_start[N2]);
  scan_finalize<<<nb2, blk, 0, stream>>>(incl, deg, bsum, row_start, cursor, N2);
  fill_csr2<<<(E + 255) / 256, blk, 0, stream>>>(edge1, edge0, cursor, csr_s, Nn, E);

  // ---- feat = node_feat @ Wt + bt ----
  gemm_mfma<<<dim3(4 * (Mp / 128)), blk, 0, stream>>>(hb, pWt, bt, featb, D, K_IN);

  // ---- two GAT hops ----
  for (int hp = 0; hp < 2; ++hp) {
    gemm_mfma<<<dim3(4 * (Mp / 128)), blk, 0, stream>>>(featb, pWf, bfp, hb, D, D);
    rowdot2_w<<<nw4, blk, 0, stream>>>(hb, w_att, sd, ss, Nn);
    gat_aggregate_w<<<nw4, blk, 0, stream>>>(featb, hb, sd, ss, edge_e, b_att,
                                             gat_bias, row_start + hp * Nn, csr_s, Nn);
  }

  // ---- fused head ----
  head_fused<<<B / 16, dim3(1024), 0, stream>>>(
      featb, tidx, pWp, bp, pDWall, dnn_b, dnn_g, dnn_be, res_g, res_be,
      Wc, bc, out);
}

// Round 9
// 340.744 us; speedup vs baseline: 1.5382x; 1.0429x over previous
//
#include <hip/hip_runtime.h>

#define D 512
typedef unsigned short ushort_t;
typedef __attribute__((ext_vector_type(8))) short bf16x8;
typedef __attribute__((ext_vector_type(4))) float f32x4;

static __device__ __forceinline__ ushort_t f2bf(float f) {
  unsigned u = __float_as_uint(f);
  u += 0x7fffu + ((u >> 16) & 1u);  // RNE
  return (ushort_t)(u >> 16);
}
static __device__ __forceinline__ float bf2f(ushort_t h) {
  return __uint_as_float(((unsigned)h) << 16);
}

static __device__ __forceinline__ void gld_lds16(const void* g, void* lds) {
  __builtin_amdgcn_global_load_lds(
      (const __attribute__((address_space(1))) unsigned int*)g,
      (__attribute__((address_space(3))) unsigned int*)lds, 16, 0, 0);
}

// ---------- weight pack: nmat x W[K][N] fp32 -> fragment-ready bf16 ----------
__global__ __launch_bounds__(256) void pack_weight(
    const float* __restrict__ W, ushort_t* __restrict__ out, int K, int N, int nmat) {
  int i = blockIdx.x * 256 + threadIdx.x;
  const int per = K * N;
  if (i >= per * nmat) return;
  const int mat = i / per;
  const int r = i - mat * per;
  const int k = r / N, n = r - k * N;
  const int nt = n >> 4, col = n & 15, kt = k >> 5, kg = (k >> 3) & 3, j = k & 7;
  out[(size_t)mat * per + (((size_t)nt * (K >> 5) + kt) << 9) + ((kg << 4) + col) * 8 + j] =
      f2bf(W[(size_t)mat * per + r]);
}

// ---------- fp32 -> bf16 row-major with row padding ----------
__global__ __launch_bounds__(256) void conv_bf16_pad(
    const float* __restrict__ in, ushort_t* __restrict__ out, int M, int Mp, int K) {
  const size_t i4 = ((size_t)blockIdx.x * 256 + threadIdx.x) * 4;
  if (i4 >= (size_t)Mp * K) return;
  const int row = (int)(i4 / K);
  ushort4 o;
  if (row < M) {
    const float4 v = *reinterpret_cast<const float4*>(&in[i4]);
    o.x = f2bf(v.x); o.y = f2bf(v.y); o.z = f2bf(v.z); o.w = f2bf(v.w);
  } else {
    o.x = o.y = o.z = o.w = 0;
  }
  *reinterpret_cast<ushort4*>(&out[i4]) = o;
}

// ---------- node MFMA GEMM, 2-phase double-buffered LDS (round-7 proven) ----
__global__ __launch_bounds__(256) void gemm_mfma(
    const ushort_t* __restrict__ A, const ushort_t* __restrict__ Bp,
    const float* __restrict__ bias, ushort_t* __restrict__ C16, int N, int K) {
  __shared__ __align__(16) ushort_t As[2][8 * 512];
  __shared__ __align__(16) ushort_t Bs[2][8 * 512];
  const int nwg = gridDim.x;
  const int q = nwg >> 3, rm = nwg & 7;
  const int xcd = blockIdx.x & 7, kk = blockIdx.x >> 3;
  const int lin = (xcd < rm ? xcd * (q + 1) : rm * (q + 1) + (xcd - rm) * q) + kk;
  const int m0 = (lin >> 2) * 128;
  const int n0 = (lin & 3) * 128;
  const int tid = threadIdx.x;
  const int lane = tid & 63;
  const int wid = tid >> 6;
  const int wm = wid >> 1, wn = wid & 1;
  const int arow = lane & 15;
  const int akoff = (lane >> 4) * 8;
  const int kt32 = K >> 5;
  f32x4 acc[4][4] = {};

  auto stage = [&](int kt, int b) {
    const int k0 = kt * 32;
    gld_lds16(&A[(size_t)(m0 + (wid * 2 + 0) * 16 + arow) * K + k0 + akoff],
              &As[b][(wid * 2 + 0) * 512]);
    gld_lds16(&A[(size_t)(m0 + (wid * 2 + 1) * 16 + arow) * K + k0 + akoff],
              &As[b][(wid * 2 + 1) * 512]);
    gld_lds16(&Bp[(((size_t)(n0 / 16 + wid * 2 + 0) * kt32 + kt) << 9) + lane * 8],
              &Bs[b][(wid * 2 + 0) * 512]);
    gld_lds16(&Bp[(((size_t)(n0 / 16 + wid * 2 + 1) * kt32 + kt) << 9) + lane * 8],
              &Bs[b][(wid * 2 + 1) * 512]);
  };

  stage(0, 0);
  __syncthreads();
  int cur = 0;
  for (int t = 0; t < kt32; ++t) {
    if (t + 1 < kt32) stage(t + 1, cur ^ 1);
    bf16x8 af[4], bfr[4];
#pragma unroll
    for (int mi = 0; mi < 4; ++mi)
      af[mi] = *reinterpret_cast<const bf16x8*>(&As[cur][(wm * 4 + mi) * 512 + lane * 8]);
#pragma unroll
    for (int ni = 0; ni < 4; ++ni)
      bfr[ni] = *reinterpret_cast<const bf16x8*>(&Bs[cur][(wn * 4 + ni) * 512 + lane * 8]);
#pragma unroll
    for (int mi = 0; mi < 4; ++mi)
#pragma unroll
      for (int ni = 0; ni < 4; ++ni)
        acc[mi][ni] = __builtin_amdgcn_mfma_f32_16x16x32_bf16(af[mi], bfr[ni], acc[mi][ni], 0, 0, 0);
    __syncthreads();
    cur ^= 1;
  }
#pragma unroll
  for (int mi = 0; mi < 4; ++mi) {
    const int row = m0 + wm * 64 + mi * 16 + ((lane >> 4) << 2);
#pragma unroll
    for (int ni = 0; ni < 4; ++ni) {
      const int col = n0 + wn * 64 + ni * 16 + (lane & 15);
      const float bv = bias[col];
#pragma unroll
      for (int r = 0; r < 4; ++r)
        C16[(size_t)(row + r) * N + col] = f2bf(acc[mi][ni][r] + bv);
    }
  }
}

// ---------- per-row double dot, one wave per row ----------
__global__ __launch_bounds__(256) void rowdot2_w(
    const ushort_t* __restrict__ hb, const float* __restrict__ w_att,
    float* __restrict__ sd, float* __restrict__ ss, int Nn) {
  const int r = blockIdx.x * 4 + (threadIdx.x >> 6);
  const int lane = threadIdx.x & 63;
  if (r >= Nn) return;
  const bf16x8 hv = *reinterpret_cast<const bf16x8*>(&hb[(size_t)r * D + lane * 8]);
  float d0 = 0.f, d1 = 0.f;
#pragma unroll
  for (int q = 0; q < 8; ++q) {
    const float v = bf2f((ushort_t)hv[q]);
    d0 += v * w_att[lane * 8 + q];
    d1 += v * w_att[D + lane * 8 + q];
  }
#pragma unroll
  for (int off = 32; off > 0; off >>= 1) {
    d0 += __shfl_xor(d0, off);
    d1 += __shfl_xor(d1, off);
  }
  if (lane == 0) { sd[r] = d0; ss[r] = d1; }
}

// ---------- bucket build: both hops, cap 64 per dst ----------
__global__ void fill_bucket(const int* __restrict__ e1, const int* __restrict__ e0,
                            int* __restrict__ cnt, int* __restrict__ bucket,
                            int Nn, int E) {
  const int e = blockIdx.x * blockDim.x + threadIdx.x;
  if (e >= E) return;
  const int d1 = e1[e];
  const int p1 = atomicAdd(&cnt[d1], 1);
  if (p1 < 64) bucket[(size_t)d1 * 64 + p1] = e1[E + e];
  const int d0 = e0[e];
  const int p0 = atomicAdd(&cnt[Nn + d0], 1);
  if (p0 < 64) bucket[((size_t)(Nn + d0)) * 64 + p0] = e0[E + e];
}

// ---------- GAT softmax + aggregate, one wave per dst, bucket-direct ----------
__global__ __launch_bounds__(256) void gat_aggregate_w(
    ushort_t* __restrict__ featb, const ushort_t* __restrict__ hb,
    const float* __restrict__ sd, const float* __restrict__ ss,
    const int* __restrict__ di, const int* __restrict__ si,
    const float* __restrict__ b_att_p, const float* __restrict__ gat_bias,
    const int* __restrict__ cnt, const int* __restrict__ bucket, int Nn, int E) {
  const int dst = blockIdx.x * 4 + (threadIdx.x >> 6);
  const int lane = threadIdx.x & 63;
  if (dst >= Nn) return;
  const int deg = cnt[dst];
  const float sdd = sd[dst];
  const float ba = b_att_p[0];
  const size_t o = (size_t)dst * D + lane * 8;
  bf16x8 fv = *reinterpret_cast<const bf16x8*>(&featb[o]);  // hoisted RMW load
  float acc[8] = {};
  if (deg <= 64) {
    const bool valid = lane < deg;
    const int slane = valid ? bucket[(size_t)dst * 64 + lane] : 0;
    const float e = valid ? tanhf(sdd + ss[slane] + ba) : -1e30f;
    float m = e;
#pragma unroll
    for (int off = 32; off > 0; off >>= 1) m = fmaxf(m, __shfl_xor(m, off));
    const float a = valid ? expf(e - m) : 0.f;
    float s = a;
#pragma unroll
    for (int off = 32; off > 0; off >>= 1) s += __shfl_xor(s, off);
    const float w = a * ((s > 0.f) ? 1.f / s : 0.f);  // per-lane alpha
    int k = 0;
    for (; k + 7 < deg; k += 8) {
      float wk[8];
      int sk[8];
#pragma unroll
      for (int u = 0; u < 8; ++u) {
        wk[u] = __shfl(w, k + u);
        sk[u] = __shfl(slane, k + u);
      }
      bf16x8 hv[8];
#pragma unroll
      for (int u = 0; u < 8; ++u)
        hv[u] = *reinterpret_cast<const bf16x8*>(&hb[(size_t)sk[u] * D + lane * 8]);
#pragma unroll
      for (int qq = 0; qq < 8; ++qq) {
        float t0 = wk[0] * bf2f((ushort_t)hv[0][qq]) + wk[1] * bf2f((ushort_t)hv[1][qq]);
        float t1 = wk[2] * bf2f((ushort_t)hv[2][qq]) + wk[3] * bf2f((ushort_t)hv[3][qq]);
        float t2 = wk[4] * bf2f((ushort_t)hv[4][qq]) + wk[5] * bf2f((ushort_t)hv[5][qq]);
        float t3 = wk[6] * bf2f((ushort_t)hv[6][qq]) + wk[7] * bf2f((ushort_t)hv[7][qq]);
        acc[qq] += (t0 + t1) + (t2 + t3);
      }
    }
    for (; k + 1 < deg; k += 2) {
      const float w0 = __shfl(w, k), w1 = __shfl(w, k + 1);
      const int s0 = __shfl(slane, k), s1 = __shfl(slane, k + 1);
      const bf16x8 h0 = *reinterpret_cast<const bf16x8*>(&hb[(size_t)s0 * D + lane * 8]);
      const bf16x8 h1 = *reinterpret_cast<const bf16x8*>(&hb[(size_t)s1 * D + lane * 8]);
#pragma unroll
      for (int qq = 0; qq < 8; ++qq)
        acc[qq] += w0 * bf2f((ushort_t)h0[qq]) + w1 * bf2f((ushort_t)h1[qq]);
    }
    if (k < deg) {
      const float wk = __shfl(w, k);
      const int sk = __shfl(slane, k);
      const bf16x8 h0 = *reinterpret_cast<const bf16x8*>(&hb[(size_t)sk * D + lane * 8]);
#pragma unroll
      for (int qq = 0; qq < 8; ++qq) acc[qq] += wk * bf2f((ushort_t)h0[qq]);
    }
  } else {
    // overflow fallback (deg > 64): ballot-scan the raw edge list. Correct for
    // any degree; effectively never taken for this graph (Poisson lambda~10).
    float m = -1e30f;
    for (int e = lane; e < E; e += 64)
      if (di[e] == dst) m = fmaxf(m, tanhf(sdd + ss[si[e]] + ba));
#pragma unroll
    for (int off = 32; off > 0; off >>= 1) m = fmaxf(m, __shfl_xor(m, off));
    float s = 0.f;
    for (int e = lane; e < E; e += 64)
      if (di[e] == dst) s += expf(tanhf(sdd + ss[si[e]] + ba) - m);
#pragma unroll
    for (int off = 32; off > 0; off >>= 1) s += __shfl_xor(s, off);
    const float inv = (s > 0.f) ? 1.f / s : 0.f;
    for (int base = 0; base < E; base += 64) {
      const int e = base + lane;
      const bool hit = (e < E) && (di[e] == dst);
      unsigned long long mask = __ballot(hit);
      const int sidx = hit ? si[e] : 0;
      const float aval = hit ? expf(tanhf(sdd + ss[sidx] + ba) - m) * inv : 0.f;
      while (mask) {
        const int l = __ffsll((long long)mask) - 1;
        mask &= mask - 1;
        const float wv = __shfl(aval, l);
        const int sk = __shfl(sidx, l);
        const bf16x8 hv = *reinterpret_cast<const bf16x8*>(&hb[(size_t)sk * D + lane * 8]);
#pragma unroll
        for (int qq = 0; qq < 8; ++qq) acc[qq] += wv * bf2f((ushort_t)hv[qq]);
      }
    }
  }
#pragma unroll
  for (int q = 0; q < 8; ++q) {
    const float f = (bf2f((ushort_t)fv[q]) + acc[q] + gat_bias[lane * 8 + q]) * 0.5f;
    fv[q] = (short)f2bf(f);
  }
  *reinterpret_cast<bf16x8*>(&featb[o]) = fv;
}

// ---------- fused head: gather -> Wp -> 2x(2x(GEMM,tanh,LN), res LN) -> logit
__global__ __launch_bounds__(1024, 4) void head_fused(
    const ushort_t* __restrict__ featb, const int* __restrict__ tidx,
    const ushort_t* __restrict__ pWp, const float* __restrict__ bp,
    const ushort_t* __restrict__ pDW, const float* __restrict__ dnn_b,
    const float* __restrict__ dnn_g, const float* __restrict__ dnn_be,
    const float* __restrict__ res_g, const float* __restrict__ res_be,
    const float* __restrict__ Wc, const float* __restrict__ bc,
    float* __restrict__ out) {
  __shared__ __align__(16) ushort_t A_lds[16 * 512];
  __shared__ float lsum[16][16], lsq[16][16], meanv[16], rsv[16];
  const int tid = threadIdx.x;
  const int lane = tid & 63;
  const int wave = tid >> 6;      // 0..15
  const int nt0 = wave * 2;       // 2 n-tiles (32 cols) per wave
  const int c15 = lane & 15;
  const int rgrp = lane >> 4;

  {
    const int row = tid >> 6, col8 = tid & 63;
    const int g = tidx[blockIdx.x * 16 + row];
    const bf16x8 v = *reinterpret_cast<const bf16x8*>(&featb[(size_t)g * D + col8 * 8]);
    *reinterpret_cast<bf16x8*>(&A_lds[row * 512 + (col8 ^ (row & 7)) * 8]) = v;
  }
  __syncthreads();

  auto do_gemm = [&](const ushort_t* __restrict__ W, f32x4& a0, f32x4& a1) {
    a0 = f32x4{0.f, 0.f, 0.f, 0.f};
    a1 = f32x4{0.f, 0.f, 0.f, 0.f};
    bf16x8 c0 = *reinterpret_cast<const bf16x8*>(
        &W[(((size_t)nt0 * 16 + 0) << 9) + lane * 8]);
    bf16x8 c1 = *reinterpret_cast<const bf16x8*>(
        &W[(((size_t)(nt0 + 1) * 16 + 0) << 9) + lane * 8]);
#pragma unroll
    for (int kt = 0; kt < 16; ++kt) {
      bf16x8 n0 = c0, n1 = c1;
      if (kt < 15) {
        n0 = *reinterpret_cast<const bf16x8*>(
            &W[(((size_t)nt0 * 16 + kt + 1) << 9) + lane * 8]);
        n1 = *reinterpret_cast<const bf16x8*>(
            &W[(((size_t)(nt0 + 1) * 16 + kt + 1) << 9) + lane * 8]);
      }
      const int col8 = kt * 4 + rgrp;
      const bf16x8 af = *reinterpret_cast<const bf16x8*>(
          &A_lds[c15 * 512 + (col8 ^ (c15 & 7)) * 8]);
      a0 = __builtin_amdgcn_mfma_f32_16x16x32_bf16(af, c0, a0, 0, 0, 0);
      a1 = __builtin_amdgcn_mfma_f32_16x16x32_bf16(af, c1, a1, 0, 0, 0);
      c0 = n0;
      c1 = n1;
    }
  };

  auto block_ln = [&](f32x4& v0, f32x4& v1, const float* __restrict__ g,
                      const float* __restrict__ be) {
    float psum[4], psq[4];
#pragma unroll
    for (int r = 0; r < 4; ++r) {
      psum[r] = v0[r] + v1[r];
      psq[r] = v0[r] * v0[r] + v1[r] * v1[r];
    }
#pragma unroll
    for (int off = 8; off > 0; off >>= 1)
#pragma unroll
      for (int r = 0; r < 4; ++r) {
        psum[r] += __shfl_xor(psum[r], off);
        psq[r] += __shfl_xor(psq[r], off);
      }
    if (c15 == 0) {
#pragma unroll
      for (int r = 0; r < 4; ++r) {
        lsum[wave][rgrp * 4 + r] = psum[r];
        lsq[wave][rgrp * 4 + r] = psq[r];
      }
    }
    __syncthreads();
    if (tid < 16) {
      float s = 0.f, qq = 0.f;
#pragma unroll
      for (int w = 0; w < 16; ++w) { s += lsum[w][tid]; qq += lsq[w][tid]; }
      const float mean = s * (1.f / 512.f);
      const float var = qq * (1.f / 512.f) - mean * mean;
      meanv[tid] = mean;
      rsv[tid] = rsqrtf(var + 1e-5f);
    }
    __syncthreads();
    const int col0 = nt0 * 16 + c15;
    const int col1 = (nt0 + 1) * 16 + c15;
    const float g0 = g[col0], b0 = be[col0];
    const float g1 = g[col1], b1 = be[col1];
#pragma unroll
    for (int r = 0; r < 4; ++r) {
      const int row = rgrp * 4 + r;
      v0[r] = (v0[r] - meanv[row]) * rsv[row] * g0 + b0;
      v1[r] = (v1[r] - meanv[row]) * rsv[row] * g1 + b1;
    }
  };

  auto store_A = [&](const f32x4& v0, const f32x4& v1) {
    const int col0 = nt0 * 16 + c15;
    const int col1 = (nt0 + 1) * 16 + c15;
#pragma unroll
    for (int r = 0; r < 4; ++r) {
      const int row = rgrp * 4 + r;
      A_lds[row * 512 + (((col0 >> 3) ^ (row & 7)) << 3) + (col0 & 7)] = f2bf(v0[r]);
      A_lds[row * 512 + (((col1 >> 3) ^ (row & 7)) << 3) + (col1 & 7)] = f2bf(v1[r]);
    }
  };

  f32x4 sc0, sc1, acc0, acc1, ln0, ln1;

  do_gemm(pWp, acc0, acc1);
  {
    const float bv0 = bp[nt0 * 16 + c15];
    const float bv1 = bp[(nt0 + 1) * 16 + c15];
#pragma unroll
    for (int r = 0; r < 4; ++r) { sc0[r] = acc0[r] + bv0; sc1[r] = acc1[r] + bv1; }
  }
  __syncthreads();
  store_A(sc0, sc1);
  __syncthreads();

  for (int rb = 0; rb < 2; ++rb) {
    {
      const int st = rb * 2;
      do_gemm(pDW + (size_t)st * D * D, acc0, acc1);
      const float bv0 = dnn_b[st * D + nt0 * 16 + c15];
      const float bv1 = dnn_b[st * D + (nt0 + 1) * 16 + c15];
#pragma unroll
      for (int r = 0; r < 4; ++r) {
        acc0[r] = tanhf(acc0[r] + bv0);
        acc1[r] = tanhf(acc1[r] + bv1);
      }
      block_ln(acc0, acc1, dnn_g + st * D, dnn_be + st * D);
      store_A(acc0, acc1);
      __syncthreads();
    }
    {
      const int st = rb * 2 + 1;
      do_gemm(pDW + (size_t)st * D * D, ln0, ln1);
      const float bv0 = dnn_b[st * D + nt0 * 16 + c15];
      const float bv1 = dnn_b[st * D + (nt0 + 1) * 16 + c15];
#pragma unroll
      for (int r = 0; r < 4; ++r) {
        ln0[r] = tanhf(ln0[r] + bv0);
        ln1[r] = tanhf(ln1[r] + bv1);
      }
      block_ln(ln0, ln1, dnn_g + st * D, dnn_be + st * D);
    }
#pragma unroll
    for (int r = 0; r < 4; ++r) {
      acc0[r] = tanhf(sc0[r] + ln0[r]);
      acc1[r] = tanhf(sc1[r] + ln1[r]);
    }
    block_ln(acc0, acc1, res_g + rb * D, res_be + rb * D);
    sc0 = acc0;
    sc1 = acc1;
    if (rb == 0) {
      store_A(sc0, sc1);
      __syncthreads();
    }
  }

  float pr[4];
  {
    const float w0 = Wc[nt0 * 16 + c15];
    const float w1 = Wc[(nt0 + 1) * 16 + c15];
#pragma unroll
    for (int r = 0; r < 4; ++r) pr[r] = sc0[r] * w0 + sc1[r] * w1;
  }
#pragma unroll
  for (int off = 8; off > 0; off >>= 1)
#pragma unroll
    for (int r = 0; r < 4; ++r) pr[r] += __shfl_xor(pr[r], off);
  __syncthreads();
  if (c15 == 0) {
#pragma unroll
    for (int r = 0; r < 4; ++r) lsum[wave][rgrp * 4 + r] = pr[r];
  }
  __syncthreads();
  if (tid < 16) {
    float s = 0.f;
#pragma unroll
    for (int w = 0; w < 16; ++w) s += lsum[w][tid];
    out[blockIdx.x * 16 + tid] = 1.f / (1.f + expf(-(s + bc[0])));
  }
}

extern "C" void kernel_launch(void* const* d_in, const int* in_sizes, int n_in,
                              void* d_out, int out_size, void* d_ws, size_t ws_size,
                              hipStream_t stream) {
  (void)n_in; (void)out_size; (void)ws_size;
  const float* node_feat = (const float*)d_in[0];
  const int* edge0 = (const int*)d_in[1];
  const int* edge1 = (const int*)d_in[2];
  const int* tidx = (const int*)d_in[3];
  const float* Wt = (const float*)d_in[4];
  const float* bt = (const float*)d_in[5];
  const float* Wf = (const float*)d_in[6];
  const float* bfp = (const float*)d_in[7];
  const float* w_att = (const float*)d_in[8];
  const float* b_att = (const float*)d_in[9];
  const float* gat_bias = (const float*)d_in[10];
  const float* Wp = (const float*)d_in[11];
  const float* bp = (const float*)d_in[12];
  const float* dnn_W = (const float*)d_in[13];
  const float* dnn_b = (const float*)d_in[14];
  const float* dnn_g = (const float*)d_in[15];
  const float* dnn_be = (const float*)d_in[16];
  const float* res_g = (const float*)d_in[17];
  const float* res_be = (const float*)d_in[18];
  const float* Wc = (const float*)d_in[19];
  const float* bc = (const float*)d_in[20];
  float* out = (float*)d_out;

  const int Nn = in_sizes[0] / D;   // 30000
  const int E = in_sizes[1] / 2;    // 300000
  const int B = in_sizes[3];        // 4096
  const int K_IN = in_sizes[4] / D; // 512
  const int Mp = (Nn + 127) / 128 * 128;
  const int N2 = 2 * Nn;

  char* p = (char*)d_ws;
  auto alloc = [&](size_t bytes) -> char* {
    char* r = p;
    p += (bytes + 255) & ~(size_t)255;
    return r;
  };
  ushort_t* featb = (ushort_t*)alloc((size_t)Mp * D * 2);
  ushort_t* hb = (ushort_t*)alloc((size_t)Mp * D * 2);  // also nfb pre-hop
  float* sd = (float*)alloc((size_t)Nn * 4);
  float* ss = (float*)alloc((size_t)Nn * 4);
  int* cnt = (int*)alloc((size_t)N2 * 4);
  int* bucket = (int*)alloc((size_t)N2 * 64 * 4);
  ushort_t* pWt = (ushort_t*)alloc((size_t)K_IN * D * 2);
  ushort_t* pWf = (ushort_t*)alloc((size_t)D * D * 2);
  ushort_t* pWp = (ushort_t*)alloc((size_t)D * D * 2);
  ushort_t* pDWall = (ushort_t*)alloc((size_t)4 * D * D * 2);

  dim3 blk(256);
  const int nw4 = (Nn + 3) / 4;

  // ---- one-time packs / converts ----
  {
    pack_weight<<<(K_IN * D + 255) / 256, blk, 0, stream>>>(Wt, pWt, K_IN, D, 1);
    pack_weight<<<(D * D + 255) / 256, blk, 0, stream>>>(Wf, pWf, D, D, 1);
    pack_weight<<<(D * D + 255) / 256, blk, 0, stream>>>(Wp, pWp, D, D, 1);
    pack_weight<<<(4 * D * D + 255) / 256, blk, 0, stream>>>(dnn_W, pDWall, D, D, 4);
    conv_bf16_pad<<<((size_t)Mp * K_IN / 4 + 255) / 256, blk, 0, stream>>>(
        node_feat, hb /*nfb*/, Nn, Mp, K_IN);
  }

  // ---- bucket build for both hops (hop1 -> segment 0, hop0 -> segment 1) ----
  hipMemsetAsync(cnt, 0, (size_t)N2 * 4, stream);
  fill_bucket<<<(E + 255) / 256, blk, 0, stream>>>(edge1, edge0, cnt, bucket, Nn, E);

  // ---- feat = node_feat @ Wt + bt ----
  gemm_mfma<<<dim3(4 * (Mp / 128)), blk, 0, stream>>>(hb, pWt, bt, featb, D, K_IN);

  // ---- two GAT hops ----
  const int* hops[2] = {edge1, edge0};
  for (int hp = 0; hp < 2; ++hp) {
    gemm_mfma<<<dim3(4 * (Mp / 128)), blk, 0, stream>>>(featb, pWf, bfp, hb, D, D);
    rowdot2_w<<<nw4, blk, 0, stream>>>(hb, w_att, sd, ss, Nn);
    gat_aggregate_w<<<nw4, blk, 0, stream>>>(
        featb, hb, sd, ss, hops[hp], hops[hp] + E, b_att, gat_bias,
        cnt + hp * Nn, bucket + (size_t)hp * Nn * 64, Nn, E);
  }

  // ---- fused head ----
  head_fused<<<B / 16, dim3(1024), 0, stream>>>(
      featb, tidx, pWp, bp, pDWall, dnn_b, dnn_g, dnn_be, res_g, res_be,
      Wc, bc, out);
}

// Round 10
// 340.248 us; speedup vs baseline: 1.5404x; 1.0015x over previous
//
#include <hip/hip_runtime.h>

#define D 512
typedef unsigned short ushort_t;
typedef __attribute__((ext_vector_type(8))) short bf16x8;
typedef __attribute__((ext_vector_type(4))) short bf16x4;
typedef __attribute__((ext_vector_type(4))) float f32x4;

static __device__ __forceinline__ ushort_t f2bf(float f) {
  unsigned u = __float_as_uint(f);
  u += 0x7fffu + ((u >> 16) & 1u);  // RNE
  return (ushort_t)(u >> 16);
}
static __device__ __forceinline__ float bf2f(ushort_t h) {
  return __uint_as_float(((unsigned)h) << 16);
}

static __device__ __forceinline__ void gld_lds16(const void* g, void* lds) {
  __builtin_amdgcn_global_load_lds(
      (const __attribute__((address_space(1))) unsigned int*)g,
      (__attribute__((address_space(3))) unsigned int*)lds, 16, 0, 0);
}

// ---------- weight pack: nmat x W[K][N] fp32 -> fragment-ready bf16 ----------
__global__ __launch_bounds__(256) void pack_weight(
    const float* __restrict__ W, ushort_t* __restrict__ out, int K, int N, int nmat) {
  int i = blockIdx.x * 256 + threadIdx.x;
  const int per = K * N;
  if (i >= per * nmat) return;
  const int mat = i / per;
  const int r = i - mat * per;
  const int k = r / N, n = r - k * N;
  const int nt = n >> 4, col = n & 15, kt = k >> 5, kg = (k >> 3) & 3, j = k & 7;
  out[(size_t)mat * per + (((size_t)nt * (K >> 5) + kt) << 9) + ((kg << 4) + col) * 8 + j] =
      f2bf(W[(size_t)mat * per + r]);
}

// ---------- fp32 -> bf16 row-major with row padding ----------
__global__ __launch_bounds__(256) void conv_bf16_pad(
    const float* __restrict__ in, ushort_t* __restrict__ out, int M, int Mp, int K) {
  const size_t i4 = ((size_t)blockIdx.x * 256 + threadIdx.x) * 4;
  if (i4 >= (size_t)Mp * K) return;
  const int row = (int)(i4 / K);
  ushort4 o;
  if (row < M) {
    const float4 v = *reinterpret_cast<const float4*>(&in[i4]);
    o.x = f2bf(v.x); o.y = f2bf(v.y); o.z = f2bf(v.z); o.w = f2bf(v.w);
  } else {
    o.x = o.y = o.z = o.w = 0;
  }
  *reinterpret_cast<ushort4*>(&out[i4]) = o;
}

// ---------- node MFMA GEMM: 128x128 tile, 8 waves (4x2), 2-phase dbuf ----
__global__ __launch_bounds__(512) void gemm_mfma(
    const ushort_t* __restrict__ A, const ushort_t* __restrict__ Bp,
    const float* __restrict__ bias, ushort_t* __restrict__ C16, int N, int K) {
  __shared__ __align__(16) ushort_t As[2][8 * 512];
  __shared__ __align__(16) ushort_t Bs[2][8 * 512];
  const int nwg = gridDim.x;
  const int q = nwg >> 3, rm = nwg & 7;
  const int xcd = blockIdx.x & 7, kk = blockIdx.x >> 3;
  const int lin = (xcd < rm ? xcd * (q + 1) : rm * (q + 1) + (xcd - rm) * q) + kk;
  const int m0 = (lin >> 2) * 128;
  const int n0 = (lin & 3) * 128;
  const int tid = threadIdx.x;
  const int lane = tid & 63;
  const int wid = tid >> 6;        // 0..7
  const int wm = wid >> 1;         // 0..3 (32-row band)
  const int wn = wid & 1;          // 0..1 (64-col band)
  const int arow = lane & 15;
  const int akoff = (lane >> 4) * 8;
  const int kt32 = K >> 5;
  f32x4 acc[2][4] = {};

  auto stage = [&](int kt, int b) {  // 2 gld per wave
    const int k0 = kt * 32;
    gld_lds16(&A[(size_t)(m0 + wid * 16 + arow) * K + k0 + akoff],
              &As[b][wid * 512]);
    gld_lds16(&Bp[(((size_t)(n0 / 16 + wid) * kt32 + kt) << 9) + lane * 8],
              &Bs[b][wid * 512]);
  };

  stage(0, 0);
  __syncthreads();
  int cur = 0;
  for (int t = 0; t < kt32; ++t) {
    if (t + 1 < kt32) stage(t + 1, cur ^ 1);
    bf16x8 af[2], bfr[4];
#pragma unroll
    for (int mi = 0; mi < 2; ++mi)
      af[mi] = *reinterpret_cast<const bf16x8*>(&As[cur][(wm * 2 + mi) * 512 + lane * 8]);
#pragma unroll
    for (int ni = 0; ni < 4; ++ni)
      bfr[ni] = *reinterpret_cast<const bf16x8*>(&Bs[cur][(wn * 4 + ni) * 512 + lane * 8]);
#pragma unroll
    for (int mi = 0; mi < 2; ++mi)
#pragma unroll
      for (int ni = 0; ni < 4; ++ni)
        acc[mi][ni] = __builtin_amdgcn_mfma_f32_16x16x32_bf16(af[mi], bfr[ni], acc[mi][ni], 0, 0, 0);
    __syncthreads();
    cur ^= 1;
  }
#pragma unroll
  for (int mi = 0; mi < 2; ++mi) {
    const int row = m0 + wm * 32 + mi * 16 + ((lane >> 4) << 2);
#pragma unroll
    for (int ni = 0; ni < 4; ++ni) {
      const int col = n0 + wn * 64 + ni * 16 + (lane & 15);
      const float bv = bias[col];
#pragma unroll
      for (int r = 0; r < 4; ++r)
        C16[(size_t)(row + r) * N + col] = f2bf(acc[mi][ni][r] + bv);
    }
  }
}

// ---------- per-row double dot, one wave per row ----------
__global__ __launch_bounds__(256) void rowdot2_w(
    const ushort_t* __restrict__ hb, const float* __restrict__ w_att,
    float* __restrict__ sd, float* __restrict__ ss, int Nn) {
  const int r = blockIdx.x * 4 + (threadIdx.x >> 6);
  const int lane = threadIdx.x & 63;
  if (r >= Nn) return;
  const bf16x8 hv = *reinterpret_cast<const bf16x8*>(&hb[(size_t)r * D + lane * 8]);
  float d0 = 0.f, d1 = 0.f;
#pragma unroll
  for (int q = 0; q < 8; ++q) {
    const float v = bf2f((ushort_t)hv[q]);
    d0 += v * w_att[lane * 8 + q];
    d1 += v * w_att[D + lane * 8 + q];
  }
#pragma unroll
  for (int off = 32; off > 0; off >>= 1) {
    d0 += __shfl_xor(d0, off);
    d1 += __shfl_xor(d1, off);
  }
  if (lane == 0) { sd[r] = d0; ss[r] = d1; }
}

// ---------- bucket build: both hops, cap 64 per dst ----------
__global__ void fill_bucket(const int* __restrict__ e1, const int* __restrict__ e0,
                            int* __restrict__ cnt, int* __restrict__ bucket,
                            int Nn, int E) {
  const int e = blockIdx.x * blockDim.x + threadIdx.x;
  if (e >= E) return;
  const int d1 = e1[e];
  const int p1 = atomicAdd(&cnt[d1], 1);
  if (p1 < 64) bucket[(size_t)d1 * 64 + p1] = e1[E + e];
  const int d0 = e0[e];
  const int p0 = atomicAdd(&cnt[Nn + d0], 1);
  if (p0 < 64) bucket[((size_t)(Nn + d0)) * 64 + p0] = e0[E + e];
}

// ---------- GAT softmax + aggregate: 2 waves per dst (256-col halves) -------
__global__ __launch_bounds__(256) void gat_aggregate_w(
    ushort_t* __restrict__ featb, const ushort_t* __restrict__ hb,
    const float* __restrict__ sd, const float* __restrict__ ss,
    const int* __restrict__ di, const int* __restrict__ si,
    const float* __restrict__ b_att_p, const float* __restrict__ gat_bias,
    const int* __restrict__ cnt, const int* __restrict__ bucket, int Nn, int E) {
  const int wave = threadIdx.x >> 6;
  const int dst = blockIdx.x * 2 + (wave >> 1);
  const int lane = threadIdx.x & 63;
  if (dst >= Nn) return;
  const int colb = (wave & 1) * 256 + lane * 4;  // this wave's 4 cols per lane
  const int deg = cnt[dst];
  const float sdd = sd[dst];
  const float ba = b_att_p[0];
  const size_t o = (size_t)dst * D + colb;
  bf16x4 fv = *reinterpret_cast<const bf16x4*>(&featb[o]);  // hoisted RMW load
  float acc[4] = {};
  if (deg <= 64) {
    const bool valid = lane < deg;
    const int slane = valid ? bucket[(size_t)dst * 64 + lane] : 0;
    const float e = valid ? tanhf(sdd + ss[slane] + ba) : -1e30f;
    float m = e;
#pragma unroll
    for (int off = 32; off > 0; off >>= 1) m = fmaxf(m, __shfl_xor(m, off));
    const float a = valid ? expf(e - m) : 0.f;
    float s = a;
#pragma unroll
    for (int off = 32; off > 0; off >>= 1) s += __shfl_xor(s, off);
    const float w = a * ((s > 0.f) ? 1.f / s : 0.f);  // per-lane alpha
    int k = 0;
    for (; k + 3 < deg; k += 4) {
      const float w0 = __shfl(w, k), w1 = __shfl(w, k + 1);
      const float w2 = __shfl(w, k + 2), w3 = __shfl(w, k + 3);
      const int s0 = __shfl(slane, k), s1 = __shfl(slane, k + 1);
      const int s2 = __shfl(slane, k + 2), s3 = __shfl(slane, k + 3);
      const bf16x4 h0 = *reinterpret_cast<const bf16x4*>(&hb[(size_t)s0 * D + colb]);
      const bf16x4 h1 = *reinterpret_cast<const bf16x4*>(&hb[(size_t)s1 * D + colb]);
      const bf16x4 h2 = *reinterpret_cast<const bf16x4*>(&hb[(size_t)s2 * D + colb]);
      const bf16x4 h3 = *reinterpret_cast<const bf16x4*>(&hb[(size_t)s3 * D + colb]);
#pragma unroll
      for (int qq = 0; qq < 4; ++qq) {
        const float t0 = w0 * bf2f((ushort_t)h0[qq]) + w1 * bf2f((ushort_t)h1[qq]);
        const float t1 = w2 * bf2f((ushort_t)h2[qq]) + w3 * bf2f((ushort_t)h3[qq]);
        acc[qq] += t0 + t1;
      }
    }
    for (; k < deg; ++k) {
      const float wk = __shfl(w, k);
      const int sk = __shfl(slane, k);
      const bf16x4 h0 = *reinterpret_cast<const bf16x4*>(&hb[(size_t)sk * D + colb]);
#pragma unroll
      for (int qq = 0; qq < 4; ++qq) acc[qq] += wk * bf2f((ushort_t)h0[qq]);
    }
  } else {
    // overflow fallback (deg > 64): ballot-scan the raw edge list. Correct for
    // any degree; effectively never taken for this graph.
    float m = -1e30f;
    for (int e = lane; e < E; e += 64)
      if (di[e] == dst) m = fmaxf(m, tanhf(sdd + ss[si[e]] + ba));
#pragma unroll
    for (int off = 32; off > 0; off >>= 1) m = fmaxf(m, __shfl_xor(m, off));
    float s = 0.f;
    for (int e = lane; e < E; e += 64)
      if (di[e] == dst) s += expf(tanhf(sdd + ss[si[e]] + ba) - m);
#pragma unroll
    for (int off = 32; off > 0; off >>= 1) s += __shfl_xor(s, off);
    const float inv = (s > 0.f) ? 1.f / s : 0.f;
    for (int base = 0; base < E; base += 64) {
      const int e = base + lane;
      const bool hit = (e < E) && (di[e] == dst);
      unsigned long long mask = __ballot(hit);
      const int sidx = hit ? si[e] : 0;
      const float aval = hit ? expf(tanhf(sdd + ss[sidx] + ba) - m) * inv : 0.f;
      while (mask) {
        const int l = __ffsll((long long)mask) - 1;
        mask &= mask - 1;
        const float wv = __shfl(aval, l);
        const int sk = __shfl(sidx, l);
        const bf16x4 hv = *reinterpret_cast<const bf16x4*>(&hb[(size_t)sk * D + colb]);
#pragma unroll
        for (int qq = 0; qq < 4; ++qq) acc[qq] += wv * bf2f((ushort_t)hv[qq]);
      }
    }
  }
#pragma unroll
  for (int q = 0; q < 4; ++q) {
    const float f = (bf2f((ushort_t)fv[q]) + acc[q] + gat_bias[colb + q]) * 0.5f;
    fv[q] = (short)f2bf(f);
  }
  *reinterpret_cast<bf16x4*>(&featb[o]) = fv;
}

// ---------- fused head: gather -> Wp -> 2x(2x(GEMM,tanh,LN), res LN) -> logit
__global__ __launch_bounds__(1024, 4) void head_fused(
    const ushort_t* __restrict__ featb, const int* __restrict__ tidx,
    const ushort_t* __restrict__ pWp, const float* __restrict__ bp,
    const ushort_t* __restrict__ pDW, const float* __restrict__ dnn_b,
    const float* __restrict__ dnn_g, const float* __restrict__ dnn_be,
    const float* __restrict__ res_g, const float* __restrict__ res_be,
    const float* __restrict__ Wc, const float* __restrict__ bc,
    float* __restrict__ out) {
  __shared__ __align__(16) ushort_t A_lds[16 * 512];
  __shared__ float lsum[16][16], lsq[16][16], meanv[16], rsv[16];
  const int tid = threadIdx.x;
  const int lane = tid & 63;
  const int wave = tid >> 6;      // 0..15
  const int nt0 = wave * 2;       // 2 n-tiles (32 cols) per wave
  const int c15 = lane & 15;
  const int rgrp = lane >> 4;

  {
    const int row = tid >> 6, col8 = tid & 63;
    const int g = tidx[blockIdx.x * 16 + row];
    const bf16x8 v = *reinterpret_cast<const bf16x8*>(&featb[(size_t)g * D + col8 * 8]);
    *reinterpret_cast<bf16x8*>(&A_lds[row * 512 + (col8 ^ (row & 7)) * 8]) = v;
  }
  __syncthreads();

  auto do_gemm = [&](const ushort_t* __restrict__ W, f32x4& a0, f32x4& a1) {
    a0 = f32x4{0.f, 0.f, 0.f, 0.f};
    a1 = f32x4{0.f, 0.f, 0.f, 0.f};
    bf16x8 c0 = *reinterpret_cast<const bf16x8*>(
        &W[(((size_t)nt0 * 16 + 0) << 9) + lane * 8]);
    bf16x8 c1 = *reinterpret_cast<const bf16x8*>(
        &W[(((size_t)(nt0 + 1) * 16 + 0) << 9) + lane * 8]);
#pragma unroll
    for (int kt = 0; kt < 16; ++kt) {
      bf16x8 n0 = c0, n1 = c1;
      if (kt < 15) {
        n0 = *reinterpret_cast<const bf16x8*>(
            &W[(((size_t)nt0 * 16 + kt + 1) << 9) + lane * 8]);
        n1 = *reinterpret_cast<const bf16x8*>(
            &W[(((size_t)(nt0 + 1) * 16 + kt + 1) << 9) + lane * 8]);
      }
      const int col8 = kt * 4 + rgrp;
      const bf16x8 af = *reinterpret_cast<const bf16x8*>(
          &A_lds[c15 * 512 + (col8 ^ (c15 & 7)) * 8]);
      a0 = __builtin_amdgcn_mfma_f32_16x16x32_bf16(af, c0, a0, 0, 0, 0);
      a1 = __builtin_amdgcn_mfma_f32_16x16x32_bf16(af, c1, a1, 0, 0, 0);
      c0 = n0;
      c1 = n1;
    }
  };

  auto block_ln = [&](f32x4& v0, f32x4& v1, const float* __restrict__ g,
                      const float* __restrict__ be) {
    float psum[4], psq[4];
#pragma unroll
    for (int r = 0; r < 4; ++r) {
      psum[r] = v0[r] + v1[r];
      psq[r] = v0[r] * v0[r] + v1[r] * v1[r];
    }
#pragma unroll
    for (int off = 8; off > 0; off >>= 1)
#pragma unroll
      for (int r = 0; r < 4; ++r) {
        psum[r] += __shfl_xor(psum[r], off);
        psq[r] += __shfl_xor(psq[r], off);
      }
    if (c15 == 0) {
#pragma unroll
      for (int r = 0; r < 4; ++r) {
        lsum[wave][rgrp * 4 + r] = psum[r];
        lsq[wave][rgrp * 4 + r] = psq[r];
      }
    }
    __syncthreads();
    if (tid < 16) {
      float s = 0.f, qq = 0.f;
#pragma unroll
      for (int w = 0; w < 16; ++w) { s += lsum[w][tid]; qq += lsq[w][tid]; }
      const float mean = s * (1.f / 512.f);
      const float var = qq * (1.f / 512.f) - mean * mean;
      meanv[tid] = mean;
      rsv[tid] = rsqrtf(var + 1e-5f);
    }
    __syncthreads();
    const int col0 = nt0 * 16 + c15;
    const int col1 = (nt0 + 1) * 16 + c15;
    const float g0 = g[col0], b0 = be[col0];
    const float g1 = g[col1], b1 = be[col1];
#pragma unroll
    for (int r = 0; r < 4; ++r) {
      const int row = rgrp * 4 + r;
      v0[r] = (v0[r] - meanv[row]) * rsv[row] * g0 + b0;
      v1[r] = (v1[r] - meanv[row]) * rsv[row] * g1 + b1;
    }
  };

  auto store_A = [&](const f32x4& v0, const f32x4& v1) {
    const int col0 = nt0 * 16 + c15;
    const int col1 = (nt0 + 1) * 16 + c15;
#pragma unroll
    for (int r = 0; r < 4; ++r) {
      const int row = rgrp * 4 + r;
      A_lds[row * 512 + (((col0 >> 3) ^ (row & 7)) << 3) + (col0 & 7)] = f2bf(v0[r]);
      A_lds[row * 512 + (((col1 >> 3) ^ (row & 7)) << 3) + (col1 & 7)] = f2bf(v1[r]);
    }
  };

  f32x4 sc0, sc1, acc0, acc1, ln0, ln1;

  do_gemm(pWp, acc0, acc1);
  {
    const float bv0 = bp[nt0 * 16 + c15];
    const float bv1 = bp[(nt0 + 1) * 16 + c15];
#pragma unroll
    for (int r = 0; r < 4; ++r) { sc0[r] = acc0[r] + bv0; sc1[r] = acc1[r] + bv1; }
  }
  __syncthreads();
  store_A(sc0, sc1);
  __syncthreads();

  for (int rb = 0; rb < 2; ++rb) {
    {
      const int st = rb * 2;
      do_gemm(pDW + (size_t)st * D * D, acc0, acc1);
      const float bv0 = dnn_b[st * D + nt0 * 16 + c15];
      const float bv1 = dnn_b[st * D + (nt0 + 1) * 16 + c15];
#pragma unroll
      for (int r = 0; r < 4; ++r) {
        acc0[r] = tanhf(acc0[r] + bv0);
        acc1[r] = tanhf(acc1[r] + bv1);
      }
      block_ln(acc0, acc1, dnn_g + st * D, dnn_be + st * D);
      store_A(acc0, acc1);
      __syncthreads();
    }
    {
      const int st = rb * 2 + 1;
      do_gemm(pDW + (size_t)st * D * D, ln0, ln1);
      const float bv0 = dnn_b[st * D + nt0 * 16 + c15];
      const float bv1 = dnn_b[st * D + (nt0 + 1) * 16 + c15];
#pragma unroll
      for (int r = 0; r < 4; ++r) {
        ln0[r] = tanhf(ln0[r] + bv0);
        ln1[r] = tanhf(ln1[r] + bv1);
      }
      block_ln(ln0, ln1, dnn_g + st * D, dnn_be + st * D);
    }
#pragma unroll
    for (int r = 0; r < 4; ++r) {
      acc0[r] = tanhf(sc0[r] + ln0[r]);
      acc1[r] = tanhf(sc1[r] + ln1[r]);
    }
    block_ln(acc0, acc1, res_g + rb * D, res_be + rb * D);
    sc0 = acc0;
    sc1 = acc1;
    if (rb == 0) {
      store_A(sc0, sc1);
      __syncthreads();
    }
  }

  float pr[4];
  {
    const float w0 = Wc[nt0 * 16 + c15];
    const float w1 = Wc[(nt0 + 1) * 16 + c15];
#pragma unroll
    for (int r = 0; r < 4; ++r) pr[r] = sc0[r] * w0 + sc1[r] * w1;
  }
#pragma unroll
  for (int off = 8; off > 0; off >>= 1)
#pragma unroll
    for (int r = 0; r < 4; ++r) pr[r] += __shfl_xor(pr[r], off);
  __syncthreads();
  if (c15 == 0) {
#pragma unroll
    for (int r = 0; r < 4; ++r) lsum[wave][rgrp * 4 + r] = pr[r];
  }
  __syncthreads();
  if (tid < 16) {
    float s = 0.f;
#pragma unroll
    for (int w = 0; w < 16; ++w) s += lsum[w][tid];
    out[blockIdx.x * 16 + tid] = 1.f / (1.f + expf(-(s + bc[0])));
  }
}

extern "C" void kernel_launch(void* const* d_in, const int* in_sizes, int n_in,
                              void* d_out, int out_size, void* d_ws, size_t ws_size,
                              hipStream_t stream) {
  (void)n_in; (void)out_size; (void)ws_size;
  const float* node_feat = (const float*)d_in[0];
  const int* edge0 = (const int*)d_in[1];
  const int* edge1 = (const int*)d_in[2];
  const int* tidx = (const int*)d_in[3];
  const float* Wt = (const float*)d_in[4];
  const float* bt = (const float*)d_in[5];
  const float* Wf = (const float*)d_in[6];
  const float* bfp = (const float*)d_in[7];
  const float* w_att = (const float*)d_in[8];
  const float* b_att = (const float*)d_in[9];
  const float* gat_bias = (const float*)d_in[10];
  const float* Wp = (const float*)d_in[11];
  const float* bp = (const float*)d_in[12];
  const float* dnn_W = (const float*)d_in[13];
  const float* dnn_b = (const float*)d_in[14];
  const float* dnn_g = (const float*)d_in[15];
  const float* dnn_be = (const float*)d_in[16];
  const float* res_g = (const float*)d_in[17];
  const float* res_be = (const float*)d_in[18];
  const float* Wc = (const float*)d_in[19];
  const float* bc = (const float*)d_in[20];
  float* out = (float*)d_out;

  const int Nn = in_sizes[0] / D;   // 30000
  const int E = in_sizes[1] / 2;    // 300000
  const int B = in_sizes[3];        // 4096
  const int K_IN = in_sizes[4] / D; // 512
  const int Mp = (Nn + 127) / 128 * 128;
  const int N2 = 2 * Nn;

  char* p = (char*)d_ws;
  auto alloc = [&](size_t bytes) -> char* {
    char* r = p;
    p += (bytes + 255) & ~(size_t)255;
    return r;
  };
  ushort_t* featb = (ushort_t*)alloc((size_t)Mp * D * 2);
  ushort_t* hb = (ushort_t*)alloc((size_t)Mp * D * 2);  // also nfb pre-hop
  float* sd = (float*)alloc((size_t)Nn * 4);
  float* ss = (float*)alloc((size_t)Nn * 4);
  int* cnt = (int*)alloc((size_t)N2 * 4);
  int* bucket = (int*)alloc((size_t)N2 * 64 * 4);
  ushort_t* pWt = (ushort_t*)alloc((size_t)K_IN * D * 2);
  ushort_t* pWf = (ushort_t*)alloc((size_t)D * D * 2);
  ushort_t* pWp = (ushort_t*)alloc((size_t)D * D * 2);
  ushort_t* pDWall = (ushort_t*)alloc((size_t)4 * D * D * 2);

  dim3 blk(256);
  const int nw2 = (Nn + 1) / 2;

  // ---- one-time packs / converts ----
  {
    pack_weight<<<(K_IN * D + 255) / 256, blk, 0, stream>>>(Wt, pWt, K_IN, D, 1);
    pack_weight<<<(D * D + 255) / 256, blk, 0, stream>>>(Wf, pWf, D, D, 1);
    pack_weight<<<(D * D + 255) / 256, blk, 0, stream>>>(Wp, pWp, D, D, 1);
    pack_weight<<<(4 * D * D + 255) / 256, blk, 0, stream>>>(dnn_W, pDWall, D, D, 4);
    conv_bf16_pad<<<((size_t)Mp * K_IN / 4 + 255) / 256, blk, 0, stream>>>(
        node_feat, hb /*nfb*/, Nn, Mp, K_IN);
  }

  // ---- bucket build for both hops (hop1 -> segment 0, hop0 -> segment 1) ----
  hipMemsetAsync(cnt, 0, (size_t)N2 * 4, stream);
  fill_bucket<<<(E + 255) / 256, blk, 0, stream>>>(edge1, edge0, cnt, bucket, Nn, E);

  // ---- feat = node_feat @ Wt + bt ----
  gemm_mfma<<<dim3(4 * (Mp / 128)), dim3(512), 0, stream>>>(hb, pWt, bt, featb, D, K_IN);

  // ---- two GAT hops ----
  const int* hops[2] = {edge1, edge0};
  for (int hp = 0; hp < 2; ++hp) {
    gemm_mfma<<<dim3(4 * (Mp / 128)), dim3(512), 0, stream>>>(featb, pWf, bfp, hb, D, D);
    rowdot2_w<<<(Nn + 3) / 4, blk, 0, stream>>>(hb, w_att, sd, ss, Nn);
    gat_aggregate_w<<<nw2, blk, 0, stream>>>(
        featb, hb, sd, ss, hops[hp], hops[hp] + E, b_att, gat_bias,
        cnt + hp * Nn, bucket + (size_t)hp * Nn * 64, Nn, E);
  }

  // ---- fused head ----
  head_fused<<<B / 16, dim3(1024), 0, stream>>>(
      featb, tidx, pWp, bp, pDWall, dnn_b, dnn_g, dnn_be, res_g, res_be,
      Wc, bc, out);
}